// Round 12
// baseline (300.596 us; speedup 1.0000x reference)
//
#include <hip/hip_runtime.h>
#include <math.h>

static constexpr int Bz = 8;
static constexpr int Lz = 2048;
static constexpr int Cz = 512;
static constexpr int CRz = 128;
static constexpr int DHz = 256;
static constexpr int MT = Bz * Lz;           // 16384 rows
static constexpr float EPSz = 1e-5f;

typedef unsigned short u16;
typedef __bf16 bf16x8 __attribute__((ext_vector_type(8)));
typedef float f32x4 __attribute__((ext_vector_type(4)));
typedef unsigned short u16x8 __attribute__((ext_vector_type(8)));

__device__ __forceinline__ float bf2f(u16 u) {
  unsigned int v = ((unsigned int)u) << 16;
  return __builtin_bit_cast(float, v);
}
__device__ __forceinline__ u16 f2bf(float f) {
  unsigned int b = __builtin_bit_cast(unsigned int, f);
  b += 0x7FFFu + ((b >> 16) & 1u);
  return (u16)(b >> 16);
}
__device__ __forceinline__ f32x4 mfma16(bf16x8 a, bf16x8 b, f32x4 c) {
  return __builtin_amdgcn_mfma_f32_16x16x32_bf16(a, b, c, 0, 0, 0);
}

// ---------------------------------------------------------------------------
// cvt: fp32 -> bf16 (8 elems/thread) — weights only
// ---------------------------------------------------------------------------
__global__ __launch_bounds__(256) void cvt_bf16_kernel(
    const float* __restrict__ src, u16* __restrict__ dst, int n8) {
  int i = blockIdx.x * 256 + threadIdx.x;
  if (i >= n8) return;
  const float4* s = (const float4*)src;
  float4 a = s[i * 2], b = s[i * 2 + 1];
  u16x8 o;
  o[0] = f2bf(a.x); o[1] = f2bf(a.y); o[2] = f2bf(a.z); o[3] = f2bf(a.w);
  o[4] = f2bf(b.x); o[5] = f2bf(b.y); o[6] = f2bf(b.z); o[7] = f2bf(b.w);
  ((u16x8*)dst)[i] = o;
}

// ---------------------------------------------------------------------------
// P: fold BN params; compute Q const vector (diff-path LN collapses to bias)
// ---------------------------------------------------------------------------
__global__ __launch_bounds__(256) void prep_kernel(
    const float* __restrict__ pw_b, const float* __restrict__ pw_g,
    const float* __restrict__ pw_bb, const float* __restrict__ pw_m,
    const float* __restrict__ pw_v,
    const float* __restrict__ dw_b, const float* __restrict__ dw_g,
    const float* __restrict__ dw_bb, const float* __restrict__ dw_m,
    const float* __restrict__ dw_v,
    const float* __restrict__ df_ln_b, const float* __restrict__ wq,
    const float* __restrict__ bq,
    float* __restrict__ pwA, float* __restrict__ pwB,
    float* __restrict__ dwA, float* __restrict__ dwB,
    float* __restrict__ qc) {
  const int blk = blockIdx.x;
  const int t = threadIdx.x;
  if (blk == 0) {
    for (int c = t; c < Cz; c += 256) {
      float inv = rsqrtf(pw_v[c] + EPSz);
      float a = pw_g[c] * inv;
      float bb = pw_bb[c] - pw_m[c] * a;
      pwA[c] = a;
      pwB[c] = pw_b[c] * a + bb;
    }
  } else if (blk <= 4) {
    const int i = blk - 1;
    for (int c = t; c < Cz; c += 256) {
      int idx = i * Cz + c;
      float inv = rsqrtf(dw_v[idx] + EPSz);
      float a = dw_g[idx] * inv;
      float bb = dw_bb[idx] - dw_m[idx] * a;
      dwA[idx] = a;
      dwB[idx] = dw_b[idx] * a + bb;
    }
  } else {
    if (t < DHz) {
      float s = bq[t];
      const float* w = wq + (size_t)t * Cz;
      for (int c = 0; c < Cz; c++) s += df_ln_b[c] * w[c];
      qc[t] = s;
    }
  }
}

// ---------------------------------------------------------------------------
// A: pointwise conv. X panel cooperatively staged (HBM-sourced, per-block
// unique); W fragments read DIRECTLY from global (L2-resident, shared by all
// blocks) -> no barriers in k-loop. LDS 41KB -> 3 blocks/CU.
// grid 512 = (bat, l-tile/32), 256 thr.
// ---------------------------------------------------------------------------
__global__ __launch_bounds__(256, 3) void pw_mfma_kernel(
    const u16* __restrict__ Wbf, const float* __restrict__ x,
    const float* __restrict__ alpha, const float* __restrict__ beta,
    u16* __restrict__ xpw) {
  __shared__ __align__(16) char lds[40960];
  u16(*sX)[520] = (u16(*)[520])lds;   // [32][520] = 33,280 B (pitch 1040, 16-aligned)
  u16* sC = (u16*)lds;                // epilogue alias [512][40] = 40,960 B
  const int bat = blockIdx.x >> 6;
  const int l0 = (blockIdx.x & 63) * 32;
  const int t = threadIdx.x;
  const int lane = t & 63, w = t >> 6;
  const int fr = lane & 15, fk = (lane >> 4) * 8;
  const int mh = (w >> 1) * 16;   // m-frag half base (o dim)
  const int nh = (w & 1) * 16;    // n rows base (l dim)
#pragma unroll
  for (int rep = 0; rep < 8; rep++) {
    const int idx = rep * 256 + t;
    const int row = idx >> 6;
    const int col = (idx & 63) * 8;
    const float* src = x + ((size_t)bat * Lz + l0 + row) * Cz + col;
    float4 f0 = *(const float4*)src;
    float4 f1 = *(const float4*)(src + 4);
    u16x8 o;
    o[0] = f2bf(f0.x); o[1] = f2bf(f0.y); o[2] = f2bf(f0.z); o[3] = f2bf(f0.w);
    o[4] = f2bf(f1.x); o[5] = f2bf(f1.y); o[6] = f2bf(f1.z); o[7] = f2bf(f1.w);
    *(u16x8*)&sX[row][col] = o;
  }
  __syncthreads();
  f32x4 acc[16];
#pragma unroll
  for (int mf = 0; mf < 16; mf++)
#pragma unroll
    for (int r = 0; r < 4; r++) acc[mf][r] = 0.f;
  const u16* aptr = Wbf + (size_t)(mh * 16 + fr) * Cz + fk;
  for (int k0 = 0; k0 < Cz; k0 += 32) {
    bf16x8 bfrag = *(const bf16x8*)&sX[nh + fr][k0 + fk];
#pragma unroll
    for (int mf = 0; mf < 16; mf++) {
      bf16x8 a = *(const bf16x8*)(aptr + (size_t)mf * 16 * Cz + k0);
      acc[mf] = mfma16(a, bfrag, acc[mf]);
    }
  }
  __syncthreads();  // sX reads done; reuse lds as sC[512][40]
#pragma unroll
  for (int mf = 0; mf < 16; mf++) {
#pragma unroll
    for (int r = 0; r < 4; r++) {
      const int o = (mh + mf) * 16 + ((lane >> 4) << 2) + r;
      const int l = nh + fr;
      float v = fmaxf(acc[mf][r] * alpha[o] + beta[o], 0.f);
      sC[o * 40 + l] = f2bf(v);
    }
  }
  __syncthreads();
#pragma unroll
  for (int rep = 0; rep < 8; rep++) {
    const int o = rep * 64 + (t >> 2);
    const int l8 = (t & 3) * 8;
    u16x8 v = *(const u16x8*)&sC[o * 40 + l8];
    *(u16x8*)(xpw + ((size_t)(bat * Cz + o)) * Lz + l0 + l8) = v;
  }
}

// ---------------------------------------------------------------------------
// B: depthwise conv, ALL 4 branches per block; padded LDS (unchanged)
// ---------------------------------------------------------------------------
template <int K>
__device__ __forceinline__ float dw_branch(const float* __restrict__ row,
                                           const float* __restrict__ wts,
                                           float a, float bb, int valid, int t,
                                           u16* __restrict__ dst) {
  constexpr int P = (K - 1) / 2;
  constexpr int W = 8 + K - 1;
  float wreg[K];
#pragma unroll
  for (int j = 0; j < K; j++) wreg[j] = wts[j];
  const int base = t * 8 - P;
  float win[W];
  if (base >= 0 && base + W <= Lz) {
#pragma unroll
    for (int j = 0; j < W; j++) {
      const int idx = base + j;
      win[j] = row[idx + (idx >> 5)];
    }
  } else {
#pragma unroll
    for (int j = 0; j < W; j++) {
      const int idx = base + j;
      win[j] = (idx >= 0 && idx < Lz) ? row[idx + (idx >> 5)] : 0.f;
    }
  }
  float acc[8] = {};
#pragma unroll
  for (int jj = 0; jj < K; jj++)
#pragma unroll
    for (int o = 0; o < 8; o++) acc[o] = fmaf(wreg[jj], win[jj + o], acc[o]);
  u16x8 ov;
  float psum = 0.f;
#pragma unroll
  for (int o = 0; o < 8; o++) {
    float v = fmaxf(acc[o] * a + bb, 0.f);
    if (t * 8 + o >= valid) v = 0.f;
    ov[o] = f2bf(v);
    psum += v;
  }
  *(u16x8*)(dst + t * 8) = ov;
  return psum;
}

__global__ __launch_bounds__(256) void dw_conv_kernel(
    const u16* __restrict__ xpw,
    const float* __restrict__ w0, const float* __restrict__ w1,
    const float* __restrict__ w2, const float* __restrict__ w3,
    const float* __restrict__ dwA, const float* __restrict__ dwB,
    u16* __restrict__ y, float* __restrict__ ysum) {
  __shared__ float row[Lz + Lz / 32];  // padded: phys = l + (l>>5)
  __shared__ float wts[48];
  __shared__ float wsum[4][4];         // [wave][branch]
  const int b = blockIdx.x >> 9;
  const int c = blockIdx.x & 511;
  const int t = threadIdx.x;
  const size_t NBL = (size_t)Bz * Cz * Lz;
  {
    u16x8 v = ((const u16x8*)(xpw + ((size_t)(b * Cz + c)) * Lz))[t];
#pragma unroll
    for (int j = 0; j < 8; j++) {
      const int idx = t * 8 + j;
      row[idx + (idx >> 5)] = bf2f(v[j]);
    }
  }
  if (t < 45) {
    float wv;
    if (t < 3) wv = w0[c * 3 + t];
    else if (t < 10) wv = w1[c * 7 + (t - 3)];
    else if (t < 25) wv = w2[c * 15 + (t - 10)];
    else wv = w3[c * 20 + (t - 25)];
    wts[t] = wv;
  }
  __syncthreads();
  u16* dstb = y + ((size_t)b * Cz + c) * Lz;
  float ps[4];
  ps[0] = dw_branch<3>(row, wts + 0, dwA[c], dwB[c], Lz, t, dstb);
  ps[1] = dw_branch<7>(row, wts + 3, dwA[Cz + c], dwB[Cz + c], Lz, t,
                       dstb + NBL);
  ps[2] = dw_branch<15>(row, wts + 10, dwA[2 * Cz + c], dwB[2 * Cz + c], Lz, t,
                        dstb + 2 * NBL);
  ps[3] = dw_branch<20>(row, wts + 25, dwA[3 * Cz + c], dwB[3 * Cz + c],
                        Lz - 1, t, dstb + 3 * NBL);
#pragma unroll
  for (int off = 32; off > 0; off >>= 1) {
#pragma unroll
    for (int i = 0; i < 4; i++) ps[i] += __shfl_down(ps[i], off, 64);
  }
  if ((t & 63) == 0) {
#pragma unroll
    for (int i = 0; i < 4; i++) wsum[t >> 6][i] = ps[i];
  }
  __syncthreads();
  if (t < 4)
    ysum[(t * Bz + b) * Cz + c] =
        wsum[0][t] + wsum[1][t] + wsum[2][t] + wsum[3][t];
}

// ---------------------------------------------------------------------------
// C: squeeze-excite (unchanged)
// ---------------------------------------------------------------------------
__global__ __launch_bounds__(128) void se_kernel(
    const float* __restrict__ ysum,
    const float* __restrict__ se_w1, const float* __restrict__ se_b1,
    const float* __restrict__ se_w2, const float* __restrict__ se_b2,
    float* __restrict__ sc) {
  const int i = blockIdx.x >> 3;
  const int b = blockIdx.x & 7;
  __shared__ float ym[Cz];
  __shared__ float h[CRz];
  const int t = threadIdx.x;
  const float* ys = ysum + (i * Bz + b) * Cz;
  for (int cc = t; cc < Cz; cc += 128) ym[cc] = ys[cc] * (1.f / Lz);
  __syncthreads();
  {
    const float* w1 = se_w1 + (size_t)i * CRz * Cz + (size_t)t * Cz;
    float s = se_b1[i * CRz + t];
    for (int cc = 0; cc < Cz; cc++) s += ym[cc] * w1[cc];
    h[t] = fmaxf(s, 0.f);
  }
  __syncthreads();
  for (int cc = t; cc < Cz; cc += 128) {
    const float* w2 = se_w2 + ((size_t)i * Cz + cc) * CRz;
    float s = se_b2[i * Cz + cc];
    for (int r = 0; r < CRz; r++) s += h[r] * w2[r];
    float wt = 1.f / (1.f + expf(-s));
    sc[(i * Bz + b) * Cz + cc] = 1.f + wt;
  }
}

// ---------------------------------------------------------------------------
// D: enhanced = LN_c( y[b,c,l]*sc[b,c] ), bf16 LDS tile (unchanged)
// ---------------------------------------------------------------------------
__global__ __launch_bounds__(256) void ln_transpose_kernel(
    const u16* __restrict__ ybuf, const float* __restrict__ scv,
    const float* __restrict__ se_ln_g, const float* __restrict__ se_ln_b,
    u16* __restrict__ ebuf) {
  __shared__ u16 tile[32][522];   // odd-word stride: conflict-free col writes
  __shared__ float ssc[Cz];
  const size_t NBL = (size_t)Bz * Cz * Lz;
  const int i = blockIdx.y >> 3;
  const int b = blockIdx.y & 7;
  const int l0 = blockIdx.x * 32;
  const int t = threadIdx.x;
  const u16* yb = ybuf + (size_t)i * NBL + (size_t)b * Cz * Lz;
  const float* scb = scv + (i * Bz + b) * Cz;
  for (int cc = t; cc < Cz; cc += 256) ssc[cc] = scb[cc];
#pragma unroll
  for (int rep = 0; rep < 8; rep++) {
    const int idx = rep * 256 + t;
    const int c = idx >> 2;
    const int l8 = (idx & 3) * 8;
    u16x8 v = *(const u16x8*)(yb + (size_t)c * Lz + l0 + l8);
#pragma unroll
    for (int j = 0; j < 8; j++) tile[l8 + j][c] = v[j];
  }
  __syncthreads();
  const int wave = t >> 6, lane = t & 63;
  const float* g = se_ln_g + i * Cz;
  const float* bb = se_ln_b + i * Cz;
  float sc8[8], g8[8], b8[8];
#pragma unroll
  for (int j = 0; j < 8; j++) {
    const int cc = lane + j * 64;
    sc8[j] = ssc[cc];
    g8[j] = g[cc];
    b8[j] = bb[cc];
  }
  u16* eb = ebuf + (size_t)i * NBL + ((size_t)b * Lz + l0) * Cz;
  for (int r = wave; r < 32; r += 4) {
    float vals[8];
    float s1 = 0.f, s2 = 0.f;
#pragma unroll
    for (int j = 0; j < 8; j++) {
      float v = bf2f(tile[r][lane + j * 64]) * sc8[j];
      vals[j] = v; s1 += v; s2 += v * v;
    }
    for (int off = 32; off > 0; off >>= 1) {
      s1 += __shfl_xor(s1, off, 64);
      s2 += __shfl_xor(s2, off, 64);
    }
    const float m = s1 * (1.f / Cz);
    const float var = s2 * (1.f / Cz) - m * m;
    const float inv = rsqrtf(var + EPSz);
#pragma unroll
    for (int j = 0; j < 8; j++) {
      const int cc = lane + j * 64;
      eb[(size_t)r * Cz + cc] = f2bf((vals[j] - m) * inv * g8[j] + b8[j]);
    }
  }
}

// ---------------------------------------------------------------------------
// E: score via MFMA, BK=64 + register prefetch (unchanged)
// ---------------------------------------------------------------------------
__global__ __launch_bounds__(256) void score_mfma_kernel(
    const u16* __restrict__ e0, const u16* __restrict__ e1,
    const u16* __restrict__ e2, const u16* __restrict__ e3,
    const u16* __restrict__ wvbf, const float* __restrict__ bv,
    const float* __restrict__ qc, const float* __restrict__ wg,
    const float* __restrict__ bg, float* __restrict__ scores) {
  __shared__ u16 sA[64][72];    // 9,216 B  (64 rows x BK=64)
  __shared__ u16 sB[256][72];   // 36,864 B (256 dh rows x BK=64)
  __shared__ float sP[4][64];
  const int i = blockIdx.y;
  const u16* E = (i == 0) ? e0 : (i == 1) ? e1 : (i == 2) ? e2 : e3;
  const int r0 = blockIdx.x * 64;
  const int t = threadIdx.x;
  const int lane = t & 63, w = t >> 6;
  const int fr = lane & 15, fk = (lane >> 4) * 8;
  const int srow = t >> 3;        // 0..31 per rep
  const int kc = (t & 7) * 8;     // k-chunk within BK=64
  u16x8 areg[2], breg[8];
#pragma unroll
  for (int rep = 0; rep < 2; rep++)
    areg[rep] = *(const u16x8*)(E + (size_t)(r0 + rep * 32 + srow) * Cz + kc);
#pragma unroll
  for (int rep = 0; rep < 8; rep++)
    breg[rep] = *(const u16x8*)(wvbf + (size_t)(rep * 32 + srow) * Cz + kc);
  f32x4 acc[4][4];
#pragma unroll
  for (int m = 0; m < 4; m++)
#pragma unroll
    for (int j = 0; j < 4; j++)
#pragma unroll
      for (int r = 0; r < 4; r++) acc[m][j][r] = 0.f;
  for (int k0 = 0; k0 < Cz; k0 += 64) {
    __syncthreads();
#pragma unroll
    for (int rep = 0; rep < 2; rep++)
      *(u16x8*)&sA[rep * 32 + srow][kc] = areg[rep];
#pragma unroll
    for (int rep = 0; rep < 8; rep++)
      *(u16x8*)&sB[rep * 32 + srow][kc] = breg[rep];
    __syncthreads();
    if (k0 + 64 < Cz) {
#pragma unroll
      for (int rep = 0; rep < 2; rep++)
        areg[rep] = *(const u16x8*)(E + (size_t)(r0 + rep * 32 + srow) * Cz +
                                    k0 + 64 + kc);
#pragma unroll
      for (int rep = 0; rep < 8; rep++)
        breg[rep] = *(const u16x8*)(wvbf + (size_t)(rep * 32 + srow) * Cz +
                                    k0 + 64 + kc);
    }
#pragma unroll
    for (int ks = 0; ks < 2; ks++) {
      bf16x8 am[4], bj[4];
#pragma unroll
      for (int m = 0; m < 4; m++)
        am[m] = *(const bf16x8*)&sA[m * 16 + fr][ks * 32 + fk];
#pragma unroll
      for (int j = 0; j < 4; j++)
        bj[j] = *(const bf16x8*)&sB[(w * 4 + j) * 16 + fr][ks * 32 + fk];
#pragma unroll
      for (int m = 0; m < 4; m++)
#pragma unroll
        for (int j = 0; j < 4; j++)
          acc[m][j] = mfma16(am[m], bj[j], acc[m][j]);
    }
  }
  float part[4][4];
#pragma unroll
  for (int m = 0; m < 4; m++)
#pragma unroll
    for (int r = 0; r < 4; r++) part[m][r] = 0.f;
#pragma unroll
  for (int j = 0; j < 4; j++) {
    const int dh = (w * 4 + j) * 16 + fr;
    const float bvn = bv[dh], qcn = qc[dh], wgn = wg[dh];
#pragma unroll
    for (int m = 0; m < 4; m++)
#pragma unroll
      for (int r = 0; r < 4; r++)
        part[m][r] += tanhf(qcn * (acc[m][j][r] + bvn)) * wgn;
  }
#pragma unroll
  for (int off = 1; off < 16; off <<= 1) {
#pragma unroll
    for (int m = 0; m < 4; m++)
#pragma unroll
      for (int r = 0; r < 4; r++)
        part[m][r] += __shfl_xor(part[m][r], off, 64);
  }
  if (fr == 0) {
#pragma unroll
    for (int m = 0; m < 4; m++)
#pragma unroll
      for (int r = 0; r < 4; r++)
        sP[w][m * 16 + ((lane >> 4) << 2) + r] = part[m][r];
  }
  __syncthreads();
  if (t < 64) {
    float s = sP[0][t] + sP[1][t] + sP[2][t] + sP[3][t] + bg[0];
    scores[(size_t)i * MT + r0 + t] = s;
  }
}

// ---------------------------------------------------------------------------
// G: fused softmax-combine + op GEMM + double-LN epilogue.
// A panel cooperatively combined+staged (unchanged from r8); op_w fragments
// read DIRECTLY from global (L2-resident) -> barrier-free k-loop.
// LDS 33.8 KB -> 4 blocks/CU. grid MT/32 = 512, 256 thr.
// ---------------------------------------------------------------------------
__global__ __launch_bounds__(256, 3) void op_mfma_kernel(
    const u16* __restrict__ e0, const u16* __restrict__ e1,
    const u16* __restrict__ e2, const u16* __restrict__ e3,
    const float* __restrict__ scores, const u16* __restrict__ opwbf,
    const float* __restrict__ opb,
    const float* __restrict__ g1, const float* __restrict__ b1,
    const float* __restrict__ x,
    const float* __restrict__ g2, const float* __restrict__ b2,
    float* __restrict__ out) {
  __shared__ u16 sA[32][520];   // combined A panel full-K, 33,280 B
  __shared__ float sw4[4][32];
  const int m0 = blockIdx.x * 32;
  const int t = threadIdx.x;
  const int lane = t & 63, w = t >> 6;
  const int fr = lane & 15, fk = (lane >> 4) * 8;
  const int mh = (w >> 1) * 16;  // m-frag base within 32-row panel (0 or 16)
  const int nh = (w & 1) * 16;   // n-frag half base (0 or 16 -> cols 0/256)
  if (t < 32) {
    const int r = m0 + t;
    float s0 = scores[r], s1 = scores[MT + r], s2 = scores[2 * MT + r],
          s3 = scores[3 * MT + r];
    float mx = fmaxf(fmaxf(s0, s1), fmaxf(s2, s3));
    float x0 = expf(s0 - mx), x1 = expf(s1 - mx), x2 = expf(s2 - mx),
          x3 = expf(s3 - mx);
    float inv = 1.f / (x0 + x1 + x2 + x3);
    sw4[0][t] = x0 * inv; sw4[1][t] = x1 * inv;
    sw4[2][t] = x2 * inv; sw4[3][t] = x3 * inv;
  }
  __syncthreads();
#pragma unroll
  for (int rep = 0; rep < 8; rep++) {
    const int idx = rep * 256 + t;
    const int row = idx >> 6;
    const int col = (idx & 63) * 8;
    const size_t off = (size_t)(m0 + row) * Cz + col;
    u16x8 v0 = *(const u16x8*)(e0 + off);
    u16x8 v1 = *(const u16x8*)(e1 + off);
    u16x8 v2 = *(const u16x8*)(e2 + off);
    u16x8 v3 = *(const u16x8*)(e3 + off);
    const float x0 = sw4[0][row], x1 = sw4[1][row], x2 = sw4[2][row],
                x3 = sw4[3][row];
    u16x8 o;
#pragma unroll
    for (int j = 0; j < 8; j++)
      o[j] = f2bf(x0 * bf2f(v0[j]) + x1 * bf2f(v1[j]) + x2 * bf2f(v2[j]) +
                  x3 * bf2f(v3[j]));
    *(u16x8*)&sA[row][col] = o;
  }
  __syncthreads();
  f32x4 acc[16];
#pragma unroll
  for (int nf = 0; nf < 16; nf++)
#pragma unroll
    for (int r = 0; r < 4; r++) acc[nf][r] = 0.f;
  const u16* bptr = opwbf + (size_t)(nh * 16 + fr) * Cz + fk;
  for (int k0 = 0; k0 < Cz; k0 += 32) {
    bf16x8 a = *(const bf16x8*)&sA[mh + fr][k0 + fk];
#pragma unroll
    for (int nf = 0; nf < 16; nf++) {
      bf16x8 b = *(const bf16x8*)(bptr + (size_t)nf * 16 * Cz + k0);
      acc[nf] = mfma16(a, b, acc[nf]);
    }
  }
  __syncthreads();  // sA reads done; reuse as sC[32][520]
  u16* sC = (u16*)&sA[0][0];
#pragma unroll
  for (int nf = 0; nf < 16; nf++) {
    const int n = (nh + nf) * 16 + fr;
    const float ob = opb[n];
#pragma unroll
    for (int r = 0; r < 4; r++) {
      const int row = mh + ((lane >> 4) << 2) + r;
      sC[row * 520 + n] = f2bf(acc[nf][r] + ob);
    }
  }
  __syncthreads();
  // ---- fused double-LN epilogue: wave handles rows w*8 .. w*8+7 ----
  float g1v[8], b1v[8], g2v[8], b2v[8];
  {
    float4 a0 = ((const float4*)g1)[lane * 2], a1 = ((const float4*)g1)[lane * 2 + 1];
    float4 c0 = ((const float4*)b1)[lane * 2], c1 = ((const float4*)b1)[lane * 2 + 1];
    float4 d0 = ((const float4*)g2)[lane * 2], d1 = ((const float4*)g2)[lane * 2 + 1];
    float4 e0v = ((const float4*)b2)[lane * 2], e1v = ((const float4*)b2)[lane * 2 + 1];
    g1v[0]=a0.x; g1v[1]=a0.y; g1v[2]=a0.z; g1v[3]=a0.w;
    g1v[4]=a1.x; g1v[5]=a1.y; g1v[6]=a1.z; g1v[7]=a1.w;
    b1v[0]=c0.x; b1v[1]=c0.y; b1v[2]=c0.z; b1v[3]=c0.w;
    b1v[4]=c1.x; b1v[5]=c1.y; b1v[6]=c1.z; b1v[7]=c1.w;
    g2v[0]=d0.x; g2v[1]=d0.y; g2v[2]=d0.z; g2v[3]=d0.w;
    g2v[4]=d1.x; g2v[5]=d1.y; g2v[6]=d1.z; g2v[7]=d1.w;
    b2v[0]=e0v.x; b2v[1]=e0v.y; b2v[2]=e0v.z; b2v[3]=e0v.w;
    b2v[4]=e1v.x; b2v[5]=e1v.y; b2v[6]=e1v.z; b2v[7]=e1v.w;
  }
  for (int rr = 0; rr < 8; rr++) {
    const int row = w * 8 + rr;
    u16x8 av = *(const u16x8*)&sC[row * 520 + lane * 8];
    float v[8];
    float s1 = 0.f, s2 = 0.f;
#pragma unroll
    for (int j = 0; j < 8; j++) {
      v[j] = bf2f(av[j]);
      s1 += v[j]; s2 += v[j] * v[j];
    }
    for (int off = 1; off < 64; off <<= 1) {
      s1 += __shfl_xor(s1, off, 64);
      s2 += __shfl_xor(s2, off, 64);
    }
    const float m1 = s1 * (1.f / Cz);
    const float iv1 = rsqrtf(s2 * (1.f / Cz) - m1 * m1 + EPSz);
    const float* xr = x + (size_t)(m0 + row) * Cz;
    float4 xa = ((const float4*)xr)[lane * 2], xb = ((const float4*)xr)[lane * 2 + 1];
    float xv[8] = {xa.x, xa.y, xa.z, xa.w, xb.x, xb.y, xb.z, xb.w};
    float tv[8];
    s1 = 0.f; s2 = 0.f;
#pragma unroll
    for (int j = 0; j < 8; j++) {
      tv[j] = (v[j] - m1) * iv1 * g1v[j] + b1v[j] + xv[j];
      s1 += tv[j]; s2 += tv[j] * tv[j];
    }
    for (int off = 1; off < 64; off <<= 1) {
      s1 += __shfl_xor(s1, off, 64);
      s2 += __shfl_xor(s2, off, 64);
    }
    const float m2 = s1 * (1.f / Cz);
    const float iv2 = rsqrtf(s2 * (1.f / Cz) - m2 * m2 + EPSz);
    float4 oa, ob;
    oa.x = (tv[0] - m2) * iv2 * g2v[0] + b2v[0];
    oa.y = (tv[1] - m2) * iv2 * g2v[1] + b2v[1];
    oa.z = (tv[2] - m2) * iv2 * g2v[2] + b2v[2];
    oa.w = (tv[3] - m2) * iv2 * g2v[3] + b2v[3];
    ob.x = (tv[4] - m2) * iv2 * g2v[4] + b2v[4];
    ob.y = (tv[5] - m2) * iv2 * g2v[5] + b2v[5];
    ob.z = (tv[6] - m2) * iv2 * g2v[6] + b2v[6];
    ob.w = (tv[7] - m2) * iv2 * g2v[7] + b2v[7];
    float* orow = out + (size_t)(m0 + row) * Cz;
    ((float4*)orow)[lane * 2] = oa;
    ((float4*)orow)[lane * 2 + 1] = ob;
  }
}

// ---------------------------------------------------------------------------
extern "C" void kernel_launch(void* const* d_in, const int* in_sizes, int n_in,
                              void* d_out, int out_size, void* d_ws,
                              size_t ws_size, hipStream_t stream) {
  const float* x = (const float*)d_in[0];
  const float* pw_w = (const float*)d_in[1];
  const float* pw_b = (const float*)d_in[2];
  const float* pw_bn_g = (const float*)d_in[3];
  const float* pw_bn_b = (const float*)d_in[4];
  const float* pw_bn_m = (const float*)d_in[5];
  const float* pw_bn_v = (const float*)d_in[6];
  const float* dw_w0 = (const float*)d_in[7];
  const float* dw_w1 = (const float*)d_in[8];
  const float* dw_w2 = (const float*)d_in[9];
  const float* dw_w3 = (const float*)d_in[10];
  const float* dw_b = (const float*)d_in[11];
  const float* dw_bn_g = (const float*)d_in[12];
  const float* dw_bn_b = (const float*)d_in[13];
  const float* dw_bn_m = (const float*)d_in[14];
  const float* dw_bn_v = (const float*)d_in[15];
  const float* se_w1 = (const float*)d_in[16];
  const float* se_b1 = (const float*)d_in[17];
  const float* se_w2 = (const float*)d_in[18];
  const float* se_b2 = (const float*)d_in[19];
  const float* se_ln_g = (const float*)d_in[20];
  const float* se_ln_b = (const float*)d_in[21];
  // d_in[22] = df_ln_g (unused: LN of channel-constant rows -> bias only)
  const float* df_ln_b = (const float*)d_in[23];
  const float* wq = (const float*)d_in[24];
  const float* bq = (const float*)d_in[25];
  const float* wv = (const float*)d_in[26];
  const float* bv = (const float*)d_in[27];
  const float* wg = (const float*)d_in[28];
  const float* bg = (const float*)d_in[29];
  const float* op_w = (const float*)d_in[30];
  const float* op_b = (const float*)d_in[31];
  const float* op_ln_g = (const float*)d_in[32];
  const float* op_ln_b = (const float*)d_in[33];
  const float* fn_g = (const float*)d_in[34];
  const float* fn_b = (const float*)d_in[35];
  float* out = (float*)d_out;

  const size_t NBL = (size_t)Bz * Cz * Lz;  // 8388608 elems
  char* p = (char*)d_ws;
  p += NBL * 2;                              // spare
  u16* xpw = (u16*)p; p += NBL * 2;          // 16MB
  u16* ybuf = (u16*)p; p += 4 * NBL * 2;     // 64MB
  u16* ebuf = (u16*)p; p += 4 * NBL * 2;     // 64MB
  u16* pwwbf = (u16*)p; p += (size_t)Cz * Cz * 2;    // 512KB
  u16* wvbf = (u16*)p; p += (size_t)DHz * Cz * 2;    // 256KB
  u16* opwbf = (u16*)p; p += (size_t)Cz * Cz * 2;    // 512KB
  float* fbuf = (float*)p;
  float* ysum = fbuf;                  // 16384
  float* scv = fbuf + 16384;           // 16384
  float* scores = fbuf + 32768;        // 65536
  float* pwA = fbuf + 98304;           // 512
  float* pwB = pwA + 512;              // 512
  float* dwA = pwB + 512;              // 2048
  float* dwB = dwA + 2048;             // 2048
  float* qc = dwB + 2048;              // 256

  cvt_bf16_kernel<<<Cz * Cz / 8 / 256, 256, 0, stream>>>(pw_w, pwwbf,
                                                         Cz * Cz / 8);
  cvt_bf16_kernel<<<DHz * Cz / 8 / 256, 256, 0, stream>>>(wv, wvbf,
                                                          DHz * Cz / 8);
  cvt_bf16_kernel<<<Cz * Cz / 8 / 256, 256, 0, stream>>>(op_w, opwbf,
                                                         Cz * Cz / 8);

  prep_kernel<<<6, 256, 0, stream>>>(pw_b, pw_bn_g, pw_bn_b, pw_bn_m, pw_bn_v,
                                     dw_b, dw_bn_g, dw_bn_b, dw_bn_m, dw_bn_v,
                                     df_ln_b, wq, bq, pwA, pwB, dwA, dwB, qc);

  pw_mfma_kernel<<<Bz * (Lz / 32), 256, 0, stream>>>(pwwbf, x, pwA, pwB, xpw);

  dw_conv_kernel<<<Bz * Cz, 256, 0, stream>>>(xpw, dw_w0, dw_w1, dw_w2, dw_w3,
                                              dwA, dwB, ybuf, ysum);

  se_kernel<<<32, 128, 0, stream>>>(ysum, se_w1, se_b1, se_w2, se_b2, scv);

  ln_transpose_kernel<<<dim3(Lz / 32, 4 * Bz), 256, 0, stream>>>(
      ybuf, scv, se_ln_g, se_ln_b, ebuf);

  score_mfma_kernel<<<dim3(MT / 64, 4), 256, 0, stream>>>(
      ebuf, ebuf + NBL, ebuf + 2 * NBL, ebuf + 3 * NBL, wvbf, bv, qc, wg, bg,
      scores);

  op_mfma_kernel<<<MT / 32, 256, 0, stream>>>(
      ebuf, ebuf + NBL, ebuf + 2 * NBL, ebuf + 3 * NBL, scores, opwbf, op_b,
      op_ln_g, op_ln_b, x, fn_g, fn_b, out);
}

// Round 13
// 229.417 us; speedup vs baseline: 1.3103x; 1.3103x over previous
//
#include <hip/hip_runtime.h>
#include <math.h>

static constexpr int Bz = 8;
static constexpr int Lz = 2048;
static constexpr int Cz = 512;
static constexpr int CRz = 128;
static constexpr int DHz = 256;
static constexpr int MT = Bz * Lz;           // 16384 rows
static constexpr float EPSz = 1e-5f;

typedef unsigned short u16;
typedef __bf16 bf16x8 __attribute__((ext_vector_type(8)));
typedef float f32x4 __attribute__((ext_vector_type(4)));
typedef unsigned short u16x8 __attribute__((ext_vector_type(8)));

__device__ __forceinline__ float bf2f(u16 u) {
  unsigned int v = ((unsigned int)u) << 16;
  return __builtin_bit_cast(float, v);
}
__device__ __forceinline__ u16 f2bf(float f) {
  unsigned int b = __builtin_bit_cast(unsigned int, f);
  b += 0x7FFFu + ((b >> 16) & 1u);
  return (u16)(b >> 16);
}
__device__ __forceinline__ f32x4 mfma16(bf16x8 a, bf16x8 b, f32x4 c) {
  return __builtin_amdgcn_mfma_f32_16x16x32_bf16(a, b, c, 0, 0, 0);
}

// ---------------------------------------------------------------------------
// cvt: fp32 -> bf16 (8 elems/thread) — weights only
// ---------------------------------------------------------------------------
__global__ __launch_bounds__(256) void cvt_bf16_kernel(
    const float* __restrict__ src, u16* __restrict__ dst, int n8) {
  int i = blockIdx.x * 256 + threadIdx.x;
  if (i >= n8) return;
  const float4* s = (const float4*)src;
  float4 a = s[i * 2], b = s[i * 2 + 1];
  u16x8 o;
  o[0] = f2bf(a.x); o[1] = f2bf(a.y); o[2] = f2bf(a.z); o[3] = f2bf(a.w);
  o[4] = f2bf(b.x); o[5] = f2bf(b.y); o[6] = f2bf(b.z); o[7] = f2bf(b.w);
  ((u16x8*)dst)[i] = o;
}

// ---------------------------------------------------------------------------
// P: fold BN params; compute Q const vector (diff-path LN collapses to bias)
// ---------------------------------------------------------------------------
__global__ __launch_bounds__(256) void prep_kernel(
    const float* __restrict__ pw_b, const float* __restrict__ pw_g,
    const float* __restrict__ pw_bb, const float* __restrict__ pw_m,
    const float* __restrict__ pw_v,
    const float* __restrict__ dw_b, const float* __restrict__ dw_g,
    const float* __restrict__ dw_bb, const float* __restrict__ dw_m,
    const float* __restrict__ dw_v,
    const float* __restrict__ df_ln_b, const float* __restrict__ wq,
    const float* __restrict__ bq,
    float* __restrict__ pwA, float* __restrict__ pwB,
    float* __restrict__ dwA, float* __restrict__ dwB,
    float* __restrict__ qc) {
  const int blk = blockIdx.x;
  const int t = threadIdx.x;
  if (blk == 0) {
    for (int c = t; c < Cz; c += 256) {
      float inv = rsqrtf(pw_v[c] + EPSz);
      float a = pw_g[c] * inv;
      float bb = pw_bb[c] - pw_m[c] * a;
      pwA[c] = a;
      pwB[c] = pw_b[c] * a + bb;
    }
  } else if (blk <= 4) {
    const int i = blk - 1;
    for (int c = t; c < Cz; c += 256) {
      int idx = i * Cz + c;
      float inv = rsqrtf(dw_v[idx] + EPSz);
      float a = dw_g[idx] * inv;
      float bb = dw_bb[idx] - dw_m[idx] * a;
      dwA[idx] = a;
      dwB[idx] = dw_b[idx] * a + bb;
    }
  } else {
    if (t < DHz) {
      float s = bq[t];
      const float* w = wq + (size_t)t * Cz;
      for (int c = 0; c < Cz; c++) s += df_ln_b[c] * w[c];
      qc[t] = s;
    }
  }
}

// ---------------------------------------------------------------------------
// A: pointwise conv. X panel staged in TWO 32x256 halves through the weight
// LDS region as scratch -> per-lane fragment registers (64 VGPR); then r8's
// exact k-loop (LDS W k-slices + reg prefetch). LDS 45KB -> 3 blocks/CU.
// grid 512 = (bat, l-tile/32), 256 thr.
// ---------------------------------------------------------------------------
__global__ __launch_bounds__(256, 3) void pw_mfma_kernel(
    const u16* __restrict__ Wbf, const float* __restrict__ x,
    const float* __restrict__ alpha, const float* __restrict__ beta,
    u16* __restrict__ xpw) {
  __shared__ __align__(16) u16 lds[512 * 40];  // 40,960 B: X-half scratch, W k-slices, sC
  __shared__ float sAl[Cz];
  __shared__ float sBe[Cz];
  const int bat = blockIdx.x >> 6;
  const int l0 = (blockIdx.x & 63) * 32;
  const int t = threadIdx.x;
  const int lane = t & 63, w = t >> 6;
  const int fr = lane & 15, fk = (lane >> 4) * 8;
  const int mh = (w >> 1) * 16;   // m-frag half base (o dim)
  const int nh = (w & 1) * 16;    // n rows base (l dim)
  for (int c = t; c < Cz; c += 256) { sAl[c] = alpha[c]; sBe[c] = beta[c]; }
  // ---- X panel -> registers, via two [32][256] LDS halves (pitch 512B) ----
  bf16x8 xregs[16];
  for (int half = 0; half < 2; half++) {
#pragma unroll
    for (int rep = 0; rep < 4; rep++) {
      const int idx = rep * 256 + t;
      const int row = idx >> 5;
      const int ch = idx & 31;
      const float* src =
          x + ((size_t)bat * Lz + l0 + row) * Cz + half * 256 + ch * 8;
      float4 f0 = *(const float4*)src;
      float4 f1 = *(const float4*)(src + 4);
      u16x8 o;
      o[0] = f2bf(f0.x); o[1] = f2bf(f0.y); o[2] = f2bf(f0.z); o[3] = f2bf(f0.w);
      o[4] = f2bf(f1.x); o[5] = f2bf(f1.y); o[6] = f2bf(f1.z); o[7] = f2bf(f1.w);
      *(u16x8*)&lds[row * 256 + ch * 8] = o;
    }
    __syncthreads();
#pragma unroll
    for (int ks = 0; ks < 8; ks++)
      xregs[half * 8 + ks] =
          *(const bf16x8*)&lds[(nh + fr) * 256 + ks * 32 + fk];
    __syncthreads();
  }
  // ---- k-loop: identical structure to r8 (W staged, reg prefetch) ----
  f32x4 acc[16];
#pragma unroll
  for (int mf = 0; mf < 16; mf++)
#pragma unroll
    for (int r = 0; r < 4; r++) acc[mf][r] = 0.f;
  const int wrow = t >> 2, wch = (t & 3) * 8;
  const u16* wbase = Wbf + (size_t)wrow * Cz + wch;
  u16x8 breg[8];
#pragma unroll
  for (int rep = 0; rep < 8; rep++)
    breg[rep] = *(const u16x8*)(wbase + (size_t)rep * 64 * Cz);
  for (int k0 = 0; k0 < Cz; k0 += 32) {
    __syncthreads();
#pragma unroll
    for (int rep = 0; rep < 8; rep++)
      *(u16x8*)&lds[(rep * 64 + wrow) * 40 + wch] = breg[rep];
    __syncthreads();
    if (k0 + 32 < Cz) {
#pragma unroll
      for (int rep = 0; rep < 8; rep++)
        breg[rep] = *(const u16x8*)(wbase + (size_t)rep * 64 * Cz + k0 + 32);
    }
    bf16x8 bfrag = xregs[k0 >> 5];
#pragma unroll
    for (int mf = 0; mf < 16; mf++) {
      bf16x8 a = *(const bf16x8*)&lds[((mh + mf) * 16 + fr) * 40 + fk];
      acc[mf] = mfma16(a, bfrag, acc[mf]);
    }
  }
  __syncthreads();  // W-slice reads done; reuse lds as sC[512][40]
  u16* sC = lds;
#pragma unroll
  for (int mf = 0; mf < 16; mf++) {
#pragma unroll
    for (int r = 0; r < 4; r++) {
      const int o = (mh + mf) * 16 + ((lane >> 4) << 2) + r;
      const int l = nh + fr;
      float v = fmaxf(acc[mf][r] * sAl[o] + sBe[o], 0.f);
      sC[o * 40 + l] = f2bf(v);
    }
  }
  __syncthreads();
#pragma unroll
  for (int rep = 0; rep < 8; rep++) {
    const int o = rep * 64 + (t >> 2);
    const int l8 = (t & 3) * 8;
    u16x8 v = *(const u16x8*)&sC[o * 40 + l8];
    *(u16x8*)(xpw + ((size_t)(bat * Cz + o)) * Lz + l0 + l8) = v;
  }
}

// ---------------------------------------------------------------------------
// B: depthwise conv, ALL 4 branches per block; padded LDS (unchanged)
// ---------------------------------------------------------------------------
template <int K>
__device__ __forceinline__ float dw_branch(const float* __restrict__ row,
                                           const float* __restrict__ wts,
                                           float a, float bb, int valid, int t,
                                           u16* __restrict__ dst) {
  constexpr int P = (K - 1) / 2;
  constexpr int W = 8 + K - 1;
  float wreg[K];
#pragma unroll
  for (int j = 0; j < K; j++) wreg[j] = wts[j];
  const int base = t * 8 - P;
  float win[W];
  if (base >= 0 && base + W <= Lz) {
#pragma unroll
    for (int j = 0; j < W; j++) {
      const int idx = base + j;
      win[j] = row[idx + (idx >> 5)];
    }
  } else {
#pragma unroll
    for (int j = 0; j < W; j++) {
      const int idx = base + j;
      win[j] = (idx >= 0 && idx < Lz) ? row[idx + (idx >> 5)] : 0.f;
    }
  }
  float acc[8] = {};
#pragma unroll
  for (int jj = 0; jj < K; jj++)
#pragma unroll
    for (int o = 0; o < 8; o++) acc[o] = fmaf(wreg[jj], win[jj + o], acc[o]);
  u16x8 ov;
  float psum = 0.f;
#pragma unroll
  for (int o = 0; o < 8; o++) {
    float v = fmaxf(acc[o] * a + bb, 0.f);
    if (t * 8 + o >= valid) v = 0.f;
    ov[o] = f2bf(v);
    psum += v;
  }
  *(u16x8*)(dst + t * 8) = ov;
  return psum;
}

__global__ __launch_bounds__(256) void dw_conv_kernel(
    const u16* __restrict__ xpw,
    const float* __restrict__ w0, const float* __restrict__ w1,
    const float* __restrict__ w2, const float* __restrict__ w3,
    const float* __restrict__ dwA, const float* __restrict__ dwB,
    u16* __restrict__ y, float* __restrict__ ysum) {
  __shared__ float row[Lz + Lz / 32];  // padded: phys = l + (l>>5)
  __shared__ float wts[48];
  __shared__ float wsum[4][4];         // [wave][branch]
  const int b = blockIdx.x >> 9;
  const int c = blockIdx.x & 511;
  const int t = threadIdx.x;
  const size_t NBL = (size_t)Bz * Cz * Lz;
  {
    u16x8 v = ((const u16x8*)(xpw + ((size_t)(b * Cz + c)) * Lz))[t];
#pragma unroll
    for (int j = 0; j < 8; j++) {
      const int idx = t * 8 + j;
      row[idx + (idx >> 5)] = bf2f(v[j]);
    }
  }
  if (t < 45) {
    float wv;
    if (t < 3) wv = w0[c * 3 + t];
    else if (t < 10) wv = w1[c * 7 + (t - 3)];
    else if (t < 25) wv = w2[c * 15 + (t - 10)];
    else wv = w3[c * 20 + (t - 25)];
    wts[t] = wv;
  }
  __syncthreads();
  u16* dstb = y + ((size_t)b * Cz + c) * Lz;
  float ps[4];
  ps[0] = dw_branch<3>(row, wts + 0, dwA[c], dwB[c], Lz, t, dstb);
  ps[1] = dw_branch<7>(row, wts + 3, dwA[Cz + c], dwB[Cz + c], Lz, t,
                       dstb + NBL);
  ps[2] = dw_branch<15>(row, wts + 10, dwA[2 * Cz + c], dwB[2 * Cz + c], Lz, t,
                        dstb + 2 * NBL);
  ps[3] = dw_branch<20>(row, wts + 25, dwA[3 * Cz + c], dwB[3 * Cz + c],
                        Lz - 1, t, dstb + 3 * NBL);
#pragma unroll
  for (int off = 32; off > 0; off >>= 1) {
#pragma unroll
    for (int i = 0; i < 4; i++) ps[i] += __shfl_down(ps[i], off, 64);
  }
  if ((t & 63) == 0) {
#pragma unroll
    for (int i = 0; i < 4; i++) wsum[t >> 6][i] = ps[i];
  }
  __syncthreads();
  if (t < 4)
    ysum[(t * Bz + b) * Cz + c] =
        wsum[0][t] + wsum[1][t] + wsum[2][t] + wsum[3][t];
}

// ---------------------------------------------------------------------------
// C: squeeze-excite (unchanged)
// ---------------------------------------------------------------------------
__global__ __launch_bounds__(128) void se_kernel(
    const float* __restrict__ ysum,
    const float* __restrict__ se_w1, const float* __restrict__ se_b1,
    const float* __restrict__ se_w2, const float* __restrict__ se_b2,
    float* __restrict__ sc) {
  const int i = blockIdx.x >> 3;
  const int b = blockIdx.x & 7;
  __shared__ float ym[Cz];
  __shared__ float h[CRz];
  const int t = threadIdx.x;
  const float* ys = ysum + (i * Bz + b) * Cz;
  for (int cc = t; cc < Cz; cc += 128) ym[cc] = ys[cc] * (1.f / Lz);
  __syncthreads();
  {
    const float* w1 = se_w1 + (size_t)i * CRz * Cz + (size_t)t * Cz;
    float s = se_b1[i * CRz + t];
    for (int cc = 0; cc < Cz; cc++) s += ym[cc] * w1[cc];
    h[t] = fmaxf(s, 0.f);
  }
  __syncthreads();
  for (int cc = t; cc < Cz; cc += 128) {
    const float* w2 = se_w2 + ((size_t)i * Cz + cc) * CRz;
    float s = se_b2[i * Cz + cc];
    for (int r = 0; r < CRz; r++) s += h[r] * w2[r];
    float wt = 1.f / (1.f + expf(-s));
    sc[(i * Bz + b) * Cz + cc] = 1.f + wt;
  }
}

// ---------------------------------------------------------------------------
// D: enhanced = LN_c( y[b,c,l]*sc[b,c] ), bf16 LDS tile (unchanged)
// ---------------------------------------------------------------------------
__global__ __launch_bounds__(256) void ln_transpose_kernel(
    const u16* __restrict__ ybuf, const float* __restrict__ scv,
    const float* __restrict__ se_ln_g, const float* __restrict__ se_ln_b,
    u16* __restrict__ ebuf) {
  __shared__ u16 tile[32][522];   // odd-word stride: conflict-free col writes
  __shared__ float ssc[Cz];
  const size_t NBL = (size_t)Bz * Cz * Lz;
  const int i = blockIdx.y >> 3;
  const int b = blockIdx.y & 7;
  const int l0 = blockIdx.x * 32;
  const int t = threadIdx.x;
  const u16* yb = ybuf + (size_t)i * NBL + (size_t)b * Cz * Lz;
  const float* scb = scv + (i * Bz + b) * Cz;
  for (int cc = t; cc < Cz; cc += 256) ssc[cc] = scb[cc];
#pragma unroll
  for (int rep = 0; rep < 8; rep++) {
    const int idx = rep * 256 + t;
    const int c = idx >> 2;
    const int l8 = (idx & 3) * 8;
    u16x8 v = *(const u16x8*)(yb + (size_t)c * Lz + l0 + l8);
#pragma unroll
    for (int j = 0; j < 8; j++) tile[l8 + j][c] = v[j];
  }
  __syncthreads();
  const int wave = t >> 6, lane = t & 63;
  const float* g = se_ln_g + i * Cz;
  const float* bb = se_ln_b + i * Cz;
  float sc8[8], g8[8], b8[8];
#pragma unroll
  for (int j = 0; j < 8; j++) {
    const int cc = lane + j * 64;
    sc8[j] = ssc[cc];
    g8[j] = g[cc];
    b8[j] = bb[cc];
  }
  u16* eb = ebuf + (size_t)i * NBL + ((size_t)b * Lz + l0) * Cz;
  for (int r = wave; r < 32; r += 4) {
    float vals[8];
    float s1 = 0.f, s2 = 0.f;
#pragma unroll
    for (int j = 0; j < 8; j++) {
      float v = bf2f(tile[r][lane + j * 64]) * sc8[j];
      vals[j] = v; s1 += v; s2 += v * v;
    }
    for (int off = 32; off > 0; off >>= 1) {
      s1 += __shfl_xor(s1, off, 64);
      s2 += __shfl_xor(s2, off, 64);
    }
    const float m = s1 * (1.f / Cz);
    const float var = s2 * (1.f / Cz) - m * m;
    const float inv = rsqrtf(var + EPSz);
#pragma unroll
    for (int j = 0; j < 8; j++) {
      const int cc = lane + j * 64;
      eb[(size_t)r * Cz + cc] = f2bf((vals[j] - m) * inv * g8[j] + b8[j]);
    }
  }
}

// ---------------------------------------------------------------------------
// E: score via MFMA, BK=64 + register prefetch (unchanged)
// ---------------------------------------------------------------------------
__global__ __launch_bounds__(256) void score_mfma_kernel(
    const u16* __restrict__ e0, const u16* __restrict__ e1,
    const u16* __restrict__ e2, const u16* __restrict__ e3,
    const u16* __restrict__ wvbf, const float* __restrict__ bv,
    const float* __restrict__ qc, const float* __restrict__ wg,
    const float* __restrict__ bg, float* __restrict__ scores) {
  __shared__ u16 sA[64][72];    // 9,216 B  (64 rows x BK=64)
  __shared__ u16 sB[256][72];   // 36,864 B (256 dh rows x BK=64)
  __shared__ float sP[4][64];
  const int i = blockIdx.y;
  const u16* E = (i == 0) ? e0 : (i == 1) ? e1 : (i == 2) ? e2 : e3;
  const int r0 = blockIdx.x * 64;
  const int t = threadIdx.x;
  const int lane = t & 63, w = t >> 6;
  const int fr = lane & 15, fk = (lane >> 4) * 8;
  const int srow = t >> 3;        // 0..31 per rep
  const int kc = (t & 7) * 8;     // k-chunk within BK=64
  u16x8 areg[2], breg[8];
#pragma unroll
  for (int rep = 0; rep < 2; rep++)
    areg[rep] = *(const u16x8*)(E + (size_t)(r0 + rep * 32 + srow) * Cz + kc);
#pragma unroll
  for (int rep = 0; rep < 8; rep++)
    breg[rep] = *(const u16x8*)(wvbf + (size_t)(rep * 32 + srow) * Cz + kc);
  f32x4 acc[4][4];
#pragma unroll
  for (int m = 0; m < 4; m++)
#pragma unroll
    for (int j = 0; j < 4; j++)
#pragma unroll
      for (int r = 0; r < 4; r++) acc[m][j][r] = 0.f;
  for (int k0 = 0; k0 < Cz; k0 += 64) {
    __syncthreads();
#pragma unroll
    for (int rep = 0; rep < 2; rep++)
      *(u16x8*)&sA[rep * 32 + srow][kc] = areg[rep];
#pragma unroll
    for (int rep = 0; rep < 8; rep++)
      *(u16x8*)&sB[rep * 32 + srow][kc] = breg[rep];
    __syncthreads();
    if (k0 + 64 < Cz) {
#pragma unroll
      for (int rep = 0; rep < 2; rep++)
        areg[rep] = *(const u16x8*)(E + (size_t)(r0 + rep * 32 + srow) * Cz +
                                    k0 + 64 + kc);
#pragma unroll
      for (int rep = 0; rep < 8; rep++)
        breg[rep] = *(const u16x8*)(wvbf + (size_t)(rep * 32 + srow) * Cz +
                                    k0 + 64 + kc);
    }
#pragma unroll
    for (int ks = 0; ks < 2; ks++) {
      bf16x8 am[4], bj[4];
#pragma unroll
      for (int m = 0; m < 4; m++)
        am[m] = *(const bf16x8*)&sA[m * 16 + fr][ks * 32 + fk];
#pragma unroll
      for (int j = 0; j < 4; j++)
        bj[j] = *(const bf16x8*)&sB[(w * 4 + j) * 16 + fr][ks * 32 + fk];
#pragma unroll
      for (int m = 0; m < 4; m++)
#pragma unroll
        for (int j = 0; j < 4; j++)
          acc[m][j] = mfma16(am[m], bj[j], acc[m][j]);
    }
  }
  float part[4][4];
#pragma unroll
  for (int m = 0; m < 4; m++)
#pragma unroll
    for (int r = 0; r < 4; r++) part[m][r] = 0.f;
#pragma unroll
  for (int j = 0; j < 4; j++) {
    const int dh = (w * 4 + j) * 16 + fr;
    const float bvn = bv[dh], qcn = qc[dh], wgn = wg[dh];
#pragma unroll
    for (int m = 0; m < 4; m++)
#pragma unroll
      for (int r = 0; r < 4; r++)
        part[m][r] += tanhf(qcn * (acc[m][j][r] + bvn)) * wgn;
  }
#pragma unroll
  for (int off = 1; off < 16; off <<= 1) {
#pragma unroll
    for (int m = 0; m < 4; m++)
#pragma unroll
      for (int r = 0; r < 4; r++)
        part[m][r] += __shfl_xor(part[m][r], off, 64);
  }
  if (fr == 0) {
#pragma unroll
    for (int m = 0; m < 4; m++)
#pragma unroll
      for (int r = 0; r < 4; r++)
        sP[w][m * 16 + ((lane >> 4) << 2) + r] = part[m][r];
  }
  __syncthreads();
  if (t < 64) {
    float s = sP[0][t] + sP[1][t] + sP[2][t] + sP[3][t] + bg[0];
    scores[(size_t)i * MT + r0 + t] = s;
  }
}

// ---------------------------------------------------------------------------
// G: fused softmax-combine + op GEMM + double-LN epilogue.
// A panel combined in TWO 32x256 halves through the B LDS region as scratch
// -> per-lane fragment registers; then r8's exact k-loop. 41.5KB -> 3 blk/CU.
// ---------------------------------------------------------------------------
__global__ __launch_bounds__(256, 3) void op_mfma_kernel(
    const u16* __restrict__ e0, const u16* __restrict__ e1,
    const u16* __restrict__ e2, const u16* __restrict__ e3,
    const float* __restrict__ scores, const u16* __restrict__ opwbf,
    const float* __restrict__ opb,
    const float* __restrict__ g1, const float* __restrict__ b1,
    const float* __restrict__ x,
    const float* __restrict__ g2, const float* __restrict__ b2,
    float* __restrict__ out) {
  __shared__ __align__(16) u16 lds[512 * 40];  // 40,960 B: A-half scratch, B k-slices, sC
  __shared__ float sw4[4][32];
  const int m0 = blockIdx.x * 32;
  const int t = threadIdx.x;
  const int lane = t & 63, w = t >> 6;
  const int fr = lane & 15, fk = (lane >> 4) * 8;
  const int mh = (w >> 1) * 16;  // m-frag base within 32-row panel (0 or 16)
  const int nh = (w & 1) * 16;   // n-frag half base (0 or 16 -> cols 0/256)
  if (t < 32) {
    const int r = m0 + t;
    float s0 = scores[r], s1 = scores[MT + r], s2 = scores[2 * MT + r],
          s3 = scores[3 * MT + r];
    float mx = fmaxf(fmaxf(s0, s1), fmaxf(s2, s3));
    float x0 = expf(s0 - mx), x1 = expf(s1 - mx), x2 = expf(s2 - mx),
          x3 = expf(s3 - mx);
    float inv = 1.f / (x0 + x1 + x2 + x3);
    sw4[0][t] = x0 * inv; sw4[1][t] = x1 * inv;
    sw4[2][t] = x2 * inv; sw4[3][t] = x3 * inv;
  }
  __syncthreads();
  // ---- combined A panel -> registers, via two [32][256] LDS halves ----
  bf16x8 aregs[16];
  for (int half = 0; half < 2; half++) {
#pragma unroll
    for (int rep = 0; rep < 4; rep++) {
      const int idx = rep * 256 + t;
      const int row = idx >> 5;
      const int ch = idx & 31;
      const size_t off = (size_t)(m0 + row) * Cz + half * 256 + ch * 8;
      u16x8 v0 = *(const u16x8*)(e0 + off);
      u16x8 v1 = *(const u16x8*)(e1 + off);
      u16x8 v2 = *(const u16x8*)(e2 + off);
      u16x8 v3 = *(const u16x8*)(e3 + off);
      const float x0 = sw4[0][row], x1 = sw4[1][row], x2 = sw4[2][row],
                  x3 = sw4[3][row];
      u16x8 o;
#pragma unroll
      for (int j = 0; j < 8; j++)
        o[j] = f2bf(x0 * bf2f(v0[j]) + x1 * bf2f(v1[j]) + x2 * bf2f(v2[j]) +
                    x3 * bf2f(v3[j]));
      *(u16x8*)&lds[row * 256 + ch * 8] = o;
    }
    __syncthreads();
#pragma unroll
    for (int ks = 0; ks < 8; ks++)
      aregs[half * 8 + ks] =
          *(const bf16x8*)&lds[(mh + fr) * 256 + ks * 32 + fk];
    __syncthreads();
  }
  // ---- k-loop: identical structure to r8 (B staged, reg prefetch) ----
  f32x4 acc[16];
#pragma unroll
  for (int nf = 0; nf < 16; nf++)
#pragma unroll
    for (int r = 0; r < 4; r++) acc[nf][r] = 0.f;
  const int wrow = t >> 2, wch = (t & 3) * 8;
  const u16* wbase = opwbf + (size_t)wrow * Cz + wch;
  u16x8 breg[8];
#pragma unroll
  for (int rep = 0; rep < 8; rep++)
    breg[rep] = *(const u16x8*)(wbase + (size_t)rep * 64 * Cz);
  for (int k0 = 0; k0 < Cz; k0 += 32) {
    __syncthreads();
#pragma unroll
    for (int rep = 0; rep < 8; rep++)
      *(u16x8*)&lds[(rep * 64 + wrow) * 40 + wch] = breg[rep];
    __syncthreads();
    if (k0 + 32 < Cz) {
#pragma unroll
      for (int rep = 0; rep < 8; rep++)
        breg[rep] = *(const u16x8*)(wbase + (size_t)rep * 64 * Cz + k0 + 32);
    }
    bf16x8 a = aregs[k0 >> 5];
#pragma unroll
    for (int nf = 0; nf < 16; nf++) {
      bf16x8 b = *(const bf16x8*)&lds[((nh + nf) * 16 + fr) * 40 + fk];
      acc[nf] = mfma16(a, b, acc[nf]);
    }
  }
  __syncthreads();  // B-slice reads done; reuse lds as sC[32][520]
  u16* sC = lds;
#pragma unroll
  for (int nf = 0; nf < 16; nf++) {
    const int n = (nh + nf) * 16 + fr;
    const float ob = opb[n];
#pragma unroll
    for (int r = 0; r < 4; r++) {
      const int row = mh + ((lane >> 4) << 2) + r;
      sC[row * 520 + n] = f2bf(acc[nf][r] + ob);
    }
  }
  __syncthreads();
  // ---- fused double-LN epilogue: wave handles rows w*8 .. w*8+7 ----
  float g1v[8], b1v[8], g2v[8], b2v[8];
  {
    float4 a0 = ((const float4*)g1)[lane * 2], a1 = ((const float4*)g1)[lane * 2 + 1];
    float4 c0 = ((const float4*)b1)[lane * 2], c1 = ((const float4*)b1)[lane * 2 + 1];
    float4 d0 = ((const float4*)g2)[lane * 2], d1 = ((const float4*)g2)[lane * 2 + 1];
    float4 e0v = ((const float4*)b2)[lane * 2], e1v = ((const float4*)b2)[lane * 2 + 1];
    g1v[0]=a0.x; g1v[1]=a0.y; g1v[2]=a0.z; g1v[3]=a0.w;
    g1v[4]=a1.x; g1v[5]=a1.y; g1v[6]=a1.z; g1v[7]=a1.w;
    b1v[0]=c0.x; b1v[1]=c0.y; b1v[2]=c0.z; b1v[3]=c0.w;
    b1v[4]=c1.x; b1v[5]=c1.y; b1v[6]=c1.z; b1v[7]=c1.w;
    g2v[0]=d0.x; g2v[1]=d0.y; g2v[2]=d0.z; g2v[3]=d0.w;
    g2v[4]=d1.x; g2v[5]=d1.y; g2v[6]=d1.z; g2v[7]=d1.w;
    b2v[0]=e0v.x; b2v[1]=e0v.y; b2v[2]=e0v.z; b2v[3]=e0v.w;
    b2v[4]=e1v.x; b2v[5]=e1v.y; b2v[6]=e1v.z; b2v[7]=e1v.w;
  }
  for (int rr = 0; rr < 8; rr++) {
    const int row = w * 8 + rr;
    u16x8 av = *(const u16x8*)&sC[row * 520 + lane * 8];
    float v[8];
    float s1 = 0.f, s2 = 0.f;
#pragma unroll
    for (int j = 0; j < 8; j++) {
      v[j] = bf2f(av[j]);
      s1 += v[j]; s2 += v[j] * v[j];
    }
    for (int off = 1; off < 64; off <<= 1) {
      s1 += __shfl_xor(s1, off, 64);
      s2 += __shfl_xor(s2, off, 64);
    }
    const float m1 = s1 * (1.f / Cz);
    const float iv1 = rsqrtf(s2 * (1.f / Cz) - m1 * m1 + EPSz);
    const float* xr = x + (size_t)(m0 + row) * Cz;
    float4 xa = ((const float4*)xr)[lane * 2], xb = ((const float4*)xr)[lane * 2 + 1];
    float xv[8] = {xa.x, xa.y, xa.z, xa.w, xb.x, xb.y, xb.z, xb.w};
    float tv[8];
    s1 = 0.f; s2 = 0.f;
#pragma unroll
    for (int j = 0; j < 8; j++) {
      tv[j] = (v[j] - m1) * iv1 * g1v[j] + b1v[j] + xv[j];
      s1 += tv[j]; s2 += tv[j] * tv[j];
    }
    for (int off = 1; off < 64; off <<= 1) {
      s1 += __shfl_xor(s1, off, 64);
      s2 += __shfl_xor(s2, off, 64);
    }
    const float m2 = s1 * (1.f / Cz);
    const float iv2 = rsqrtf(s2 * (1.f / Cz) - m2 * m2 + EPSz);
    float4 oa, ob;
    oa.x = (tv[0] - m2) * iv2 * g2v[0] + b2v[0];
    oa.y = (tv[1] - m2) * iv2 * g2v[1] + b2v[1];
    oa.z = (tv[2] - m2) * iv2 * g2v[2] + b2v[2];
    oa.w = (tv[3] - m2) * iv2 * g2v[3] + b2v[3];
    ob.x = (tv[4] - m2) * iv2 * g2v[4] + b2v[4];
    ob.y = (tv[5] - m2) * iv2 * g2v[5] + b2v[5];
    ob.z = (tv[6] - m2) * iv2 * g2v[6] + b2v[6];
    ob.w = (tv[7] - m2) * iv2 * g2v[7] + b2v[7];
    float* orow = out + (size_t)(m0 + row) * Cz;
    ((float4*)orow)[lane * 2] = oa;
    ((float4*)orow)[lane * 2 + 1] = ob;
  }
}

// ---------------------------------------------------------------------------
extern "C" void kernel_launch(void* const* d_in, const int* in_sizes, int n_in,
                              void* d_out, int out_size, void* d_ws,
                              size_t ws_size, hipStream_t stream) {
  const float* x = (const float*)d_in[0];
  const float* pw_w = (const float*)d_in[1];
  const float* pw_b = (const float*)d_in[2];
  const float* pw_bn_g = (const float*)d_in[3];
  const float* pw_bn_b = (const float*)d_in[4];
  const float* pw_bn_m = (const float*)d_in[5];
  const float* pw_bn_v = (const float*)d_in[6];
  const float* dw_w0 = (const float*)d_in[7];
  const float* dw_w1 = (const float*)d_in[8];
  const float* dw_w2 = (const float*)d_in[9];
  const float* dw_w3 = (const float*)d_in[10];
  const float* dw_b = (const float*)d_in[11];
  const float* dw_bn_g = (const float*)d_in[12];
  const float* dw_bn_b = (const float*)d_in[13];
  const float* dw_bn_m = (const float*)d_in[14];
  const float* dw_bn_v = (const float*)d_in[15];
  const float* se_w1 = (const float*)d_in[16];
  const float* se_b1 = (const float*)d_in[17];
  const float* se_w2 = (const float*)d_in[18];
  const float* se_b2 = (const float*)d_in[19];
  const float* se_ln_g = (const float*)d_in[20];
  const float* se_ln_b = (const float*)d_in[21];
  // d_in[22] = df_ln_g (unused: LN of channel-constant rows -> bias only)
  const float* df_ln_b = (const float*)d_in[23];
  const float* wq = (const float*)d_in[24];
  const float* bq = (const float*)d_in[25];
  const float* wv = (const float*)d_in[26];
  const float* bv = (const float*)d_in[27];
  const float* wg = (const float*)d_in[28];
  const float* bg = (const float*)d_in[29];
  const float* op_w = (const float*)d_in[30];
  const float* op_b = (const float*)d_in[31];
  const float* op_ln_g = (const float*)d_in[32];
  const float* op_ln_b = (const float*)d_in[33];
  const float* fn_g = (const float*)d_in[34];
  const float* fn_b = (const float*)d_in[35];
  float* out = (float*)d_out;

  const size_t NBL = (size_t)Bz * Cz * Lz;  // 8388608 elems
  char* p = (char*)d_ws;
  p += NBL * 2;                              // spare
  u16* xpw = (u16*)p; p += NBL * 2;          // 16MB
  u16* ybuf = (u16*)p; p += 4 * NBL * 2;     // 64MB
  u16* ebuf = (u16*)p; p += 4 * NBL * 2;     // 64MB
  u16* pwwbf = (u16*)p; p += (size_t)Cz * Cz * 2;    // 512KB
  u16* wvbf = (u16*)p; p += (size_t)DHz * Cz * 2;    // 256KB
  u16* opwbf = (u16*)p; p += (size_t)Cz * Cz * 2;    // 512KB
  float* fbuf = (float*)p;
  float* ysum = fbuf;                  // 16384
  float* scv = fbuf + 16384;           // 16384
  float* scores = fbuf + 32768;        // 65536
  float* pwA = fbuf + 98304;           // 512
  float* pwB = pwA + 512;              // 512
  float* dwA = pwB + 512;              // 2048
  float* dwB = dwA + 2048;             // 2048
  float* qc = dwB + 2048;              // 256

  cvt_bf16_kernel<<<Cz * Cz / 8 / 256, 256, 0, stream>>>(pw_w, pwwbf,
                                                         Cz * Cz / 8);
  cvt_bf16_kernel<<<DHz * Cz / 8 / 256, 256, 0, stream>>>(wv, wvbf,
                                                          DHz * Cz / 8);
  cvt_bf16_kernel<<<Cz * Cz / 8 / 256, 256, 0, stream>>>(op_w, opwbf,
                                                         Cz * Cz / 8);

  prep_kernel<<<6, 256, 0, stream>>>(pw_b, pw_bn_g, pw_bn_b, pw_bn_m, pw_bn_v,
                                     dw_b, dw_bn_g, dw_bn_b, dw_bn_m, dw_bn_v,
                                     df_ln_b, wq, bq, pwA, pwB, dwA, dwB, qc);

  pw_mfma_kernel<<<Bz * (Lz / 32), 256, 0, stream>>>(pwwbf, x, pwA, pwB, xpw);

  dw_conv_kernel<<<Bz * Cz, 256, 0, stream>>>(xpw, dw_w0, dw_w1, dw_w2, dw_w3,
                                              dwA, dwB, ybuf, ysum);

  se_kernel<<<32, 128, 0, stream>>>(ysum, se_w1, se_b1, se_w2, se_b2, scv);

  ln_transpose_kernel<<<dim3(Lz / 32, 4 * Bz), 256, 0, stream>>>(
      ybuf, scv, se_ln_g, se_ln_b, ebuf);

  score_mfma_kernel<<<dim3(MT / 64, 4), 256, 0, stream>>>(
      ebuf, ebuf + NBL, ebuf + 2 * NBL, ebuf + 3 * NBL, wvbf, bv, qc, wg, bg,
      scores);

  op_mfma_kernel<<<MT / 32, 256, 0, stream>>>(
      ebuf, ebuf + NBL, ebuf + 2 * NBL, ebuf + 3 * NBL, scores, opwbf, op_b,
      op_ln_g, op_ln_b, x, fn_g, fn_b, out);
}

// Round 14
// 203.170 us; speedup vs baseline: 1.4795x; 1.1292x over previous
//
#include <hip/hip_runtime.h>
#include <math.h>

static constexpr int Bz = 8;
static constexpr int Lz = 2048;
static constexpr int Cz = 512;
static constexpr int CRz = 128;
static constexpr int DHz = 256;
static constexpr int MT = Bz * Lz;           // 16384 rows
static constexpr float EPSz = 1e-5f;

typedef unsigned short u16;
typedef __bf16 bf16x8 __attribute__((ext_vector_type(8)));
typedef float f32x4 __attribute__((ext_vector_type(4)));
typedef unsigned short u16x8 __attribute__((ext_vector_type(8)));

__device__ __forceinline__ float bf2f(u16 u) {
  unsigned int v = ((unsigned int)u) << 16;
  return __builtin_bit_cast(float, v);
}
__device__ __forceinline__ u16 f2bf(float f) {
  unsigned int b = __builtin_bit_cast(unsigned int, f);
  b += 0x7FFFu + ((b >> 16) & 1u);
  return (u16)(b >> 16);
}
__device__ __forceinline__ f32x4 mfma16(bf16x8 a, bf16x8 b, f32x4 c) {
  return __builtin_amdgcn_mfma_f32_16x16x32_bf16(a, b, c, 0, 0, 0);
}

// ---------------------------------------------------------------------------
// P: merged weight-cvt (pw_w, wv, op_w) + BN fold + Q const vector.
// grid 326: [0,128) pw_w, [128,192) wv, [192,320) op_w, [320,326) prep.
// Per-element expressions identical to the former cvt/prep kernels.
// ---------------------------------------------------------------------------
__global__ __launch_bounds__(256) void prep_cvt_kernel(
    const float* __restrict__ pw_w, const float* __restrict__ wv,
    const float* __restrict__ op_w,
    u16* __restrict__ pwwbf, u16* __restrict__ wvbf, u16* __restrict__ opwbf,
    const float* __restrict__ pw_b, const float* __restrict__ pw_g,
    const float* __restrict__ pw_bb, const float* __restrict__ pw_m,
    const float* __restrict__ pw_v,
    const float* __restrict__ dw_b, const float* __restrict__ dw_g,
    const float* __restrict__ dw_bb, const float* __restrict__ dw_m,
    const float* __restrict__ dw_v,
    const float* __restrict__ df_ln_b, const float* __restrict__ wq,
    const float* __restrict__ bq,
    float* __restrict__ pwA, float* __restrict__ pwB,
    float* __restrict__ dwA, float* __restrict__ dwB,
    float* __restrict__ qc) {
  const int blk = blockIdx.x;
  const int t = threadIdx.x;
  if (blk < 320) {
    const float* src;
    u16* dst;
    int i;
    if (blk < 128) { src = pw_w; dst = pwwbf; i = blk; }
    else if (blk < 192) { src = wv; dst = wvbf; i = blk - 128; }
    else { src = op_w; dst = opwbf; i = blk - 192; }
    const int idx = i * 256 + t;
    const float4* s = (const float4*)src;
    float4 a = s[idx * 2], b = s[idx * 2 + 1];
    u16x8 o;
    o[0] = f2bf(a.x); o[1] = f2bf(a.y); o[2] = f2bf(a.z); o[3] = f2bf(a.w);
    o[4] = f2bf(b.x); o[5] = f2bf(b.y); o[6] = f2bf(b.z); o[7] = f2bf(b.w);
    ((u16x8*)dst)[idx] = o;
    return;
  }
  const int sec = blk - 320;
  if (sec == 0) {
    for (int c = t; c < Cz; c += 256) {
      float inv = rsqrtf(pw_v[c] + EPSz);
      float a = pw_g[c] * inv;
      float bb = pw_bb[c] - pw_m[c] * a;
      pwA[c] = a;
      pwB[c] = pw_b[c] * a + bb;
    }
  } else if (sec <= 4) {
    const int i = sec - 1;
    for (int c = t; c < Cz; c += 256) {
      int idx = i * Cz + c;
      float inv = rsqrtf(dw_v[idx] + EPSz);
      float a = dw_g[idx] * inv;
      float bb = dw_bb[idx] - dw_m[idx] * a;
      dwA[idx] = a;
      dwB[idx] = dw_b[idx] * a + bb;
    }
  } else {
    // Q = df_ln_b @ wq.T + bq (diff-path LN collapses to its bias)
    if (t < DHz) {
      float s = bq[t];
      const float* w = wq + (size_t)t * Cz;
      for (int c = 0; c < Cz; c++) s += df_ln_b[c] * w[c];
      qc[t] = s;
    }
  }
}

// ---------------------------------------------------------------------------
// A: pointwise conv, panel-resident (round-8 verified, byte-identical)
// ---------------------------------------------------------------------------
__global__ __launch_bounds__(256, 2) void pw_mfma_kernel(
    const u16* __restrict__ Wbf, const float* __restrict__ x,
    const float* __restrict__ alpha, const float* __restrict__ beta,
    u16* __restrict__ xpw) {
  __shared__ __align__(16) char lds[74240];
  u16(*sX)[520] = (u16(*)[520])lds;                  // [32][520] = 33,280 B
  u16(*sW)[40] = (u16(*)[40])(lds + 33280);          // [512][40] = 40,960 B
  u16* sC = (u16*)(lds + 33280);                     // [512][40] epilogue alias
  __shared__ float sAl[Cz];
  __shared__ float sBe[Cz];
  const int bat = blockIdx.x >> 6;
  const int l0 = (blockIdx.x & 63) * 32;
  const int t = threadIdx.x;
  const int lane = t & 63, w = t >> 6;
  const int fr = lane & 15, fk = (lane >> 4) * 8;
  const int mh = (w >> 1) * 16;   // m-frag half base (o dim)
  const int nh = (w & 1) * 16;    // n rows base (l dim)
#pragma unroll
  for (int rep = 0; rep < 8; rep++) {
    const int idx = rep * 256 + t;
    const int row = idx >> 6;
    const int col = (idx & 63) * 8;
    const float* src = x + ((size_t)bat * Lz + l0 + row) * Cz + col;
    float4 f0 = *(const float4*)src;
    float4 f1 = *(const float4*)(src + 4);
    u16x8 o;
    o[0] = f2bf(f0.x); o[1] = f2bf(f0.y); o[2] = f2bf(f0.z); o[3] = f2bf(f0.w);
    o[4] = f2bf(f1.x); o[5] = f2bf(f1.y); o[6] = f2bf(f1.z); o[7] = f2bf(f1.w);
    *(u16x8*)&sX[row][col] = o;
  }
  for (int c = t; c < Cz; c += 256) { sAl[c] = alpha[c]; sBe[c] = beta[c]; }
  f32x4 acc[16];
#pragma unroll
  for (int mf = 0; mf < 16; mf++)
#pragma unroll
    for (int r = 0; r < 4; r++) acc[mf][r] = 0.f;
  const int wrow = t >> 2, wch = (t & 3) * 8;
  const u16* wbase = Wbf + (size_t)wrow * Cz + wch;
  u16x8 breg[8];
#pragma unroll
  for (int rep = 0; rep < 8; rep++)
    breg[rep] = *(const u16x8*)(wbase + (size_t)rep * 64 * Cz);
  for (int k0 = 0; k0 < Cz; k0 += 32) {
    __syncthreads();
#pragma unroll
    for (int rep = 0; rep < 8; rep++)
      *(u16x8*)&sW[rep * 64 + wrow][wch] = breg[rep];
    __syncthreads();
    if (k0 + 32 < Cz) {
#pragma unroll
      for (int rep = 0; rep < 8; rep++)
        breg[rep] = *(const u16x8*)(wbase + (size_t)rep * 64 * Cz + k0 + 32);
    }
    bf16x8 bfrag = *(const bf16x8*)&sX[nh + fr][k0 + fk];
#pragma unroll
    for (int mf = 0; mf < 16; mf++) {
      bf16x8 a = *(const bf16x8*)&sW[(mh + mf) * 16 + fr][fk];
      acc[mf] = mfma16(a, bfrag, acc[mf]);
    }
  }
  __syncthreads();  // sW reads done; reuse as sC[512][40]
#pragma unroll
  for (int mf = 0; mf < 16; mf++) {
#pragma unroll
    for (int r = 0; r < 4; r++) {
      const int o = (mh + mf) * 16 + ((lane >> 4) << 2) + r;
      const int l = nh + fr;
      float v = fmaxf(acc[mf][r] * sAl[o] + sBe[o], 0.f);
      sC[o * 40 + l] = f2bf(v);
    }
  }
  __syncthreads();
#pragma unroll
  for (int rep = 0; rep < 8; rep++) {
    const int o = rep * 64 + (t >> 2);
    const int l8 = (t & 3) * 8;
    u16x8 v = *(const u16x8*)&sC[o * 40 + l8];
    *(u16x8*)(xpw + ((size_t)(bat * Cz + o)) * Lz + l0 + l8) = v;
  }
}

// ---------------------------------------------------------------------------
// B: depthwise conv, ALL 4 branches per block; padded LDS (unchanged)
// ---------------------------------------------------------------------------
template <int K>
__device__ __forceinline__ float dw_branch(const float* __restrict__ row,
                                           const float* __restrict__ wts,
                                           float a, float bb, int valid, int t,
                                           u16* __restrict__ dst) {
  constexpr int P = (K - 1) / 2;
  constexpr int W = 8 + K - 1;
  float wreg[K];
#pragma unroll
  for (int j = 0; j < K; j++) wreg[j] = wts[j];
  const int base = t * 8 - P;
  float win[W];
  if (base >= 0 && base + W <= Lz) {
#pragma unroll
    for (int j = 0; j < W; j++) {
      const int idx = base + j;
      win[j] = row[idx + (idx >> 5)];
    }
  } else {
#pragma unroll
    for (int j = 0; j < W; j++) {
      const int idx = base + j;
      win[j] = (idx >= 0 && idx < Lz) ? row[idx + (idx >> 5)] : 0.f;
    }
  }
  float acc[8] = {};
#pragma unroll
  for (int jj = 0; jj < K; jj++)
#pragma unroll
    for (int o = 0; o < 8; o++) acc[o] = fmaf(wreg[jj], win[jj + o], acc[o]);
  u16x8 ov;
  float psum = 0.f;
#pragma unroll
  for (int o = 0; o < 8; o++) {
    float v = fmaxf(acc[o] * a + bb, 0.f);
    if (t * 8 + o >= valid) v = 0.f;
    ov[o] = f2bf(v);
    psum += v;
  }
  *(u16x8*)(dst + t * 8) = ov;
  return psum;
}

__global__ __launch_bounds__(256) void dw_conv_kernel(
    const u16* __restrict__ xpw,
    const float* __restrict__ w0, const float* __restrict__ w1,
    const float* __restrict__ w2, const float* __restrict__ w3,
    const float* __restrict__ dwA, const float* __restrict__ dwB,
    u16* __restrict__ y, float* __restrict__ ysum) {
  __shared__ float row[Lz + Lz / 32];  // padded: phys = l + (l>>5)
  __shared__ float wts[48];
  __shared__ float wsum[4][4];         // [wave][branch]
  const int b = blockIdx.x >> 9;
  const int c = blockIdx.x & 511;
  const int t = threadIdx.x;
  const size_t NBL = (size_t)Bz * Cz * Lz;
  {
    u16x8 v = ((const u16x8*)(xpw + ((size_t)(b * Cz + c)) * Lz))[t];
#pragma unroll
    for (int j = 0; j < 8; j++) {
      const int idx = t * 8 + j;
      row[idx + (idx >> 5)] = bf2f(v[j]);
    }
  }
  if (t < 45) {
    float wv;
    if (t < 3) wv = w0[c * 3 + t];
    else if (t < 10) wv = w1[c * 7 + (t - 3)];
    else if (t < 25) wv = w2[c * 15 + (t - 10)];
    else wv = w3[c * 20 + (t - 25)];
    wts[t] = wv;
  }
  __syncthreads();
  u16* dstb = y + ((size_t)b * Cz + c) * Lz;
  float ps[4];
  ps[0] = dw_branch<3>(row, wts + 0, dwA[c], dwB[c], Lz, t, dstb);
  ps[1] = dw_branch<7>(row, wts + 3, dwA[Cz + c], dwB[Cz + c], Lz, t,
                       dstb + NBL);
  ps[2] = dw_branch<15>(row, wts + 10, dwA[2 * Cz + c], dwB[2 * Cz + c], Lz, t,
                        dstb + 2 * NBL);
  ps[3] = dw_branch<20>(row, wts + 25, dwA[3 * Cz + c], dwB[3 * Cz + c],
                        Lz - 1, t, dstb + 3 * NBL);
#pragma unroll
  for (int off = 32; off > 0; off >>= 1) {
#pragma unroll
    for (int i = 0; i < 4; i++) ps[i] += __shfl_down(ps[i], off, 64);
  }
  if ((t & 63) == 0) {
#pragma unroll
    for (int i = 0; i < 4; i++) wsum[t >> 6][i] = ps[i];
  }
  __syncthreads();
  if (t < 4)
    ysum[(t * Bz + b) * Cz + c] =
        wsum[0][t] + wsum[1][t] + wsum[2][t] + wsum[3][t];
}

// ---------------------------------------------------------------------------
// C: squeeze-excite
// ---------------------------------------------------------------------------
__global__ __launch_bounds__(128) void se_kernel(
    const float* __restrict__ ysum,
    const float* __restrict__ se_w1, const float* __restrict__ se_b1,
    const float* __restrict__ se_w2, const float* __restrict__ se_b2,
    float* __restrict__ sc) {
  const int i = blockIdx.x >> 3;
  const int b = blockIdx.x & 7;
  __shared__ float ym[Cz];
  __shared__ float h[CRz];
  const int t = threadIdx.x;
  const float* ys = ysum + (i * Bz + b) * Cz;
  for (int cc = t; cc < Cz; cc += 128) ym[cc] = ys[cc] * (1.f / Lz);
  __syncthreads();
  {
    const float* w1 = se_w1 + (size_t)i * CRz * Cz + (size_t)t * Cz;
    float s = se_b1[i * CRz + t];
    for (int cc = 0; cc < Cz; cc++) s += ym[cc] * w1[cc];
    h[t] = fmaxf(s, 0.f);
  }
  __syncthreads();
  for (int cc = t; cc < Cz; cc += 128) {
    const float* w2 = se_w2 + ((size_t)i * Cz + cc) * CRz;
    float s = se_b2[i * Cz + cc];
    for (int r = 0; r < CRz; r++) s += h[r] * w2[r];
    float wt = 1.f / (1.f + expf(-s));
    sc[(i * Bz + b) * Cz + cc] = 1.f + wt;
  }
}

// ---------------------------------------------------------------------------
// D: enhanced = LN_c( y[b,c,l]*sc[b,c] ), bf16 LDS tile (stride 522)
// ---------------------------------------------------------------------------
__global__ __launch_bounds__(256) void ln_transpose_kernel(
    const u16* __restrict__ ybuf, const float* __restrict__ scv,
    const float* __restrict__ se_ln_g, const float* __restrict__ se_ln_b,
    u16* __restrict__ ebuf) {
  __shared__ u16 tile[32][522];   // odd-word stride: conflict-free col writes
  __shared__ float ssc[Cz];
  const size_t NBL = (size_t)Bz * Cz * Lz;
  const int i = blockIdx.y >> 3;
  const int b = blockIdx.y & 7;
  const int l0 = blockIdx.x * 32;
  const int t = threadIdx.x;
  const u16* yb = ybuf + (size_t)i * NBL + (size_t)b * Cz * Lz;
  const float* scb = scv + (i * Bz + b) * Cz;
  for (int cc = t; cc < Cz; cc += 256) ssc[cc] = scb[cc];
#pragma unroll
  for (int rep = 0; rep < 8; rep++) {
    const int idx = rep * 256 + t;
    const int c = idx >> 2;
    const int l8 = (idx & 3) * 8;
    u16x8 v = *(const u16x8*)(yb + (size_t)c * Lz + l0 + l8);
#pragma unroll
    for (int j = 0; j < 8; j++) tile[l8 + j][c] = v[j];
  }
  __syncthreads();
  const int wave = t >> 6, lane = t & 63;
  const float* g = se_ln_g + i * Cz;
  const float* bb = se_ln_b + i * Cz;
  float sc8[8], g8[8], b8[8];
#pragma unroll
  for (int j = 0; j < 8; j++) {
    const int cc = lane + j * 64;
    sc8[j] = ssc[cc];
    g8[j] = g[cc];
    b8[j] = bb[cc];
  }
  u16* eb = ebuf + (size_t)i * NBL + ((size_t)b * Lz + l0) * Cz;
  for (int r = wave; r < 32; r += 4) {
    float vals[8];
    float s1 = 0.f, s2 = 0.f;
#pragma unroll
    for (int j = 0; j < 8; j++) {
      float v = bf2f(tile[r][lane + j * 64]) * sc8[j];
      vals[j] = v; s1 += v; s2 += v * v;
    }
    for (int off = 32; off > 0; off >>= 1) {
      s1 += __shfl_xor(s1, off, 64);
      s2 += __shfl_xor(s2, off, 64);
    }
    const float m = s1 * (1.f / Cz);
    const float var = s2 * (1.f / Cz) - m * m;
    const float inv = rsqrtf(var + EPSz);
#pragma unroll
    for (int j = 0; j < 8; j++) {
      const int cc = lane + j * 64;
      eb[(size_t)r * Cz + cc] = f2bf((vals[j] - m) * inv * g8[j] + b8[j]);
    }
  }
}

// ---------------------------------------------------------------------------
// E: score via MFMA, BK=64 + register prefetch
// ---------------------------------------------------------------------------
__global__ __launch_bounds__(256) void score_mfma_kernel(
    const u16* __restrict__ e0, const u16* __restrict__ e1,
    const u16* __restrict__ e2, const u16* __restrict__ e3,
    const u16* __restrict__ wvbf, const float* __restrict__ bv,
    const float* __restrict__ qc, const float* __restrict__ wg,
    const float* __restrict__ bg, float* __restrict__ scores) {
  __shared__ u16 sA[64][72];    // 9,216 B  (64 rows x BK=64)
  __shared__ u16 sB[256][72];   // 36,864 B (256 dh rows x BK=64)
  __shared__ float sP[4][64];
  const int i = blockIdx.y;
  const u16* E = (i == 0) ? e0 : (i == 1) ? e1 : (i == 2) ? e2 : e3;
  const int r0 = blockIdx.x * 64;
  const int t = threadIdx.x;
  const int lane = t & 63, w = t >> 6;
  const int fr = lane & 15, fk = (lane >> 4) * 8;
  const int srow = t >> 3;        // 0..31 per rep
  const int kc = (t & 7) * 8;     // k-chunk within BK=64
  u16x8 areg[2], breg[8];
#pragma unroll
  for (int rep = 0; rep < 2; rep++)
    areg[rep] = *(const u16x8*)(E + (size_t)(r0 + rep * 32 + srow) * Cz + kc);
#pragma unroll
  for (int rep = 0; rep < 8; rep++)
    breg[rep] = *(const u16x8*)(wvbf + (size_t)(rep * 32 + srow) * Cz + kc);
  f32x4 acc[4][4];
#pragma unroll
  for (int m = 0; m < 4; m++)
#pragma unroll
    for (int j = 0; j < 4; j++)
#pragma unroll
      for (int r = 0; r < 4; r++) acc[m][j][r] = 0.f;
  for (int k0 = 0; k0 < Cz; k0 += 64) {
    __syncthreads();
#pragma unroll
    for (int rep = 0; rep < 2; rep++)
      *(u16x8*)&sA[rep * 32 + srow][kc] = areg[rep];
#pragma unroll
    for (int rep = 0; rep < 8; rep++)
      *(u16x8*)&sB[rep * 32 + srow][kc] = breg[rep];
    __syncthreads();
    if (k0 + 64 < Cz) {
#pragma unroll
      for (int rep = 0; rep < 2; rep++)
        areg[rep] = *(const u16x8*)(E + (size_t)(r0 + rep * 32 + srow) * Cz +
                                    k0 + 64 + kc);
#pragma unroll
      for (int rep = 0; rep < 8; rep++)
        breg[rep] = *(const u16x8*)(wvbf + (size_t)(rep * 32 + srow) * Cz +
                                    k0 + 64 + kc);
    }
#pragma unroll
    for (int ks = 0; ks < 2; ks++) {
      bf16x8 am[4], bj[4];
#pragma unroll
      for (int m = 0; m < 4; m++)
        am[m] = *(const bf16x8*)&sA[m * 16 + fr][ks * 32 + fk];
#pragma unroll
      for (int j = 0; j < 4; j++)
        bj[j] = *(const bf16x8*)&sB[(w * 4 + j) * 16 + fr][ks * 32 + fk];
#pragma unroll
      for (int m = 0; m < 4; m++)
#pragma unroll
        for (int j = 0; j < 4; j++)
          acc[m][j] = mfma16(am[m], bj[j], acc[m][j]);
    }
  }
  float part[4][4];
#pragma unroll
  for (int m = 0; m < 4; m++)
#pragma unroll
    for (int r = 0; r < 4; r++) part[m][r] = 0.f;
#pragma unroll
  for (int j = 0; j < 4; j++) {
    const int dh = (w * 4 + j) * 16 + fr;
    const float bvn = bv[dh], qcn = qc[dh], wgn = wg[dh];
#pragma unroll
    for (int m = 0; m < 4; m++)
#pragma unroll
      for (int r = 0; r < 4; r++)
        part[m][r] += tanhf(qcn * (acc[m][j][r] + bvn)) * wgn;
  }
#pragma unroll
  for (int off = 1; off < 16; off <<= 1) {
#pragma unroll
    for (int m = 0; m < 4; m++)
#pragma unroll
      for (int r = 0; r < 4; r++)
        part[m][r] += __shfl_xor(part[m][r], off, 64);
  }
  if (fr == 0) {
#pragma unroll
    for (int m = 0; m < 4; m++)
#pragma unroll
      for (int r = 0; r < 4; r++)
        sP[w][m * 16 + ((lane >> 4) << 2) + r] = part[m][r];
  }
  __syncthreads();
  if (t < 64) {
    float s = sP[0][t] + sP[1][t] + sP[2][t] + sP[3][t] + bg[0];
    scores[(size_t)i * MT + r0 + t] = s;
  }
}

// ---------------------------------------------------------------------------
// G: fused softmax-combine + op GEMM + DOUBLE-LN epilogue (round-8 verified)
// ---------------------------------------------------------------------------
__global__ __launch_bounds__(256, 2) void op_mfma_kernel(
    const u16* __restrict__ e0, const u16* __restrict__ e1,
    const u16* __restrict__ e2, const u16* __restrict__ e3,
    const float* __restrict__ scores, const u16* __restrict__ opwbf,
    const float* __restrict__ opb,
    const float* __restrict__ g1, const float* __restrict__ b1,
    const float* __restrict__ x,
    const float* __restrict__ g2, const float* __restrict__ b2,
    float* __restrict__ out) {
  __shared__ u16 sA[32][520];   // combined A panel full-K, 33,280 B
  __shared__ u16 sB[512][40];   // op_w k-slice, 40,960 B
  __shared__ float sw4[4][32];
  const int m0 = blockIdx.x * 32;
  const int t = threadIdx.x;
  const int lane = t & 63, w = t >> 6;
  const int fr = lane & 15, fk = (lane >> 4) * 8;
  const int mh = (w >> 1) * 16;  // m-frag base within 32-row panel (0 or 16)
  const int nh = (w & 1) * 16;   // n-frag half base (0 or 16 -> cols 0/256)
  if (t < 32) {
    const int r = m0 + t;
    float s0 = scores[r], s1 = scores[MT + r], s2 = scores[2 * MT + r],
          s3 = scores[3 * MT + r];
    float mx = fmaxf(fmaxf(s0, s1), fmaxf(s2, s3));
    float x0 = expf(s0 - mx), x1 = expf(s1 - mx), x2 = expf(s2 - mx),
          x3 = expf(s3 - mx);
    float inv = 1.f / (x0 + x1 + x2 + x3);
    sw4[0][t] = x0 * inv; sw4[1][t] = x1 * inv;
    sw4[2][t] = x2 * inv; sw4[3][t] = x3 * inv;
  }
  __syncthreads();
#pragma unroll
  for (int rep = 0; rep < 8; rep++) {
    const int idx = rep * 256 + t;
    const int row = idx >> 6;
    const int col = (idx & 63) * 8;
    const size_t off = (size_t)(m0 + row) * Cz + col;
    u16x8 v0 = *(const u16x8*)(e0 + off);
    u16x8 v1 = *(const u16x8*)(e1 + off);
    u16x8 v2 = *(const u16x8*)(e2 + off);
    u16x8 v3 = *(const u16x8*)(e3 + off);
    const float x0 = sw4[0][row], x1 = sw4[1][row], x2 = sw4[2][row],
                x3 = sw4[3][row];
    u16x8 o;
#pragma unroll
    for (int j = 0; j < 8; j++)
      o[j] = f2bf(x0 * bf2f(v0[j]) + x1 * bf2f(v1[j]) + x2 * bf2f(v2[j]) +
                  x3 * bf2f(v3[j]));
    *(u16x8*)&sA[row][col] = o;
  }
  f32x4 acc[16];
#pragma unroll
  for (int nf = 0; nf < 16; nf++)
#pragma unroll
    for (int r = 0; r < 4; r++) acc[nf][r] = 0.f;
  const int wrow = t >> 2, wch = (t & 3) * 8;
  const u16* wbase = opwbf + (size_t)wrow * Cz + wch;
  u16x8 breg[8];
#pragma unroll
  for (int rep = 0; rep < 8; rep++)
    breg[rep] = *(const u16x8*)(wbase + (size_t)rep * 64 * Cz);
  for (int k0 = 0; k0 < Cz; k0 += 32) {
    __syncthreads();
#pragma unroll
    for (int rep = 0; rep < 8; rep++)
      *(u16x8*)&sB[rep * 64 + wrow][wch] = breg[rep];
    __syncthreads();
    if (k0 + 32 < Cz) {
#pragma unroll
      for (int rep = 0; rep < 8; rep++)
        breg[rep] = *(const u16x8*)(wbase + (size_t)rep * 64 * Cz + k0 + 32);
    }
    bf16x8 a = *(const bf16x8*)&sA[mh + fr][k0 + fk];
#pragma unroll
    for (int nf = 0; nf < 16; nf++) {
      bf16x8 b = *(const bf16x8*)&sB[(nh + nf) * 16 + fr][fk];
      acc[nf] = mfma16(a, b, acc[nf]);
    }
  }
  __syncthreads();  // all sA/sB reads done; reuse sA as sC[32][520]
  u16* sC = (u16*)&sA[0][0];
#pragma unroll
  for (int nf = 0; nf < 16; nf++) {
    const int n = (nh + nf) * 16 + fr;
    const float ob = opb[n];
#pragma unroll
    for (int r = 0; r < 4; r++) {
      const int row = mh + ((lane >> 4) << 2) + r;
      sC[row * 520 + n] = f2bf(acc[nf][r] + ob);
    }
  }
  __syncthreads();
  // ---- fused double-LN epilogue: wave handles rows w*8 .. w*8+7 ----
  float g1v[8], b1v[8], g2v[8], b2v[8];
  {
    float4 a0 = ((const float4*)g1)[lane * 2], a1 = ((const float4*)g1)[lane * 2 + 1];
    float4 c0 = ((const float4*)b1)[lane * 2], c1 = ((const float4*)b1)[lane * 2 + 1];
    float4 d0 = ((const float4*)g2)[lane * 2], d1 = ((const float4*)g2)[lane * 2 + 1];
    float4 e0v = ((const float4*)b2)[lane * 2], e1v = ((const float4*)b2)[lane * 2 + 1];
    g1v[0]=a0.x; g1v[1]=a0.y; g1v[2]=a0.z; g1v[3]=a0.w;
    g1v[4]=a1.x; g1v[5]=a1.y; g1v[6]=a1.z; g1v[7]=a1.w;
    b1v[0]=c0.x; b1v[1]=c0.y; b1v[2]=c0.z; b1v[3]=c0.w;
    b1v[4]=c1.x; b1v[5]=c1.y; b1v[6]=c1.z; b1v[7]=c1.w;
    g2v[0]=d0.x; g2v[1]=d0.y; g2v[2]=d0.z; g2v[3]=d0.w;
    g2v[4]=d1.x; g2v[5]=d1.y; g2v[6]=d1.z; g2v[7]=d1.w;
    b2v[0]=e0v.x; b2v[1]=e0v.y; b2v[2]=e0v.z; b2v[3]=e0v.w;
    b2v[4]=e1v.x; b2v[5]=e1v.y; b2v[6]=e1v.z; b2v[7]=e1v.w;
  }
  for (int rr = 0; rr < 8; rr++) {
    const int row = w * 8 + rr;
    u16x8 av = *(const u16x8*)&sC[row * 520 + lane * 8];
    float v[8];
    float s1 = 0.f, s2 = 0.f;
#pragma unroll
    for (int j = 0; j < 8; j++) {
      v[j] = bf2f(av[j]);
      s1 += v[j]; s2 += v[j] * v[j];
    }
    for (int off = 1; off < 64; off <<= 1) {
      s1 += __shfl_xor(s1, off, 64);
      s2 += __shfl_xor(s2, off, 64);
    }
    const float m1 = s1 * (1.f / Cz);
    const float iv1 = rsqrtf(s2 * (1.f / Cz) - m1 * m1 + EPSz);
    const float* xr = x + (size_t)(m0 + row) * Cz;
    float4 xa = ((const float4*)xr)[lane * 2], xb = ((const float4*)xr)[lane * 2 + 1];
    float xv[8] = {xa.x, xa.y, xa.z, xa.w, xb.x, xb.y, xb.z, xb.w};
    float tv[8];
    s1 = 0.f; s2 = 0.f;
#pragma unroll
    for (int j = 0; j < 8; j++) {
      tv[j] = (v[j] - m1) * iv1 * g1v[j] + b1v[j] + xv[j];
      s1 += tv[j]; s2 += tv[j] * tv[j];
    }
    for (int off = 1; off < 64; off <<= 1) {
      s1 += __shfl_xor(s1, off, 64);
      s2 += __shfl_xor(s2, off, 64);
    }
    const float m2 = s1 * (1.f / Cz);
    const float iv2 = rsqrtf(s2 * (1.f / Cz) - m2 * m2 + EPSz);
    float4 oa, ob;
    oa.x = (tv[0] - m2) * iv2 * g2v[0] + b2v[0];
    oa.y = (tv[1] - m2) * iv2 * g2v[1] + b2v[1];
    oa.z = (tv[2] - m2) * iv2 * g2v[2] + b2v[2];
    oa.w = (tv[3] - m2) * iv2 * g2v[3] + b2v[3];
    ob.x = (tv[4] - m2) * iv2 * g2v[4] + b2v[4];
    ob.y = (tv[5] - m2) * iv2 * g2v[5] + b2v[5];
    ob.z = (tv[6] - m2) * iv2 * g2v[6] + b2v[6];
    ob.w = (tv[7] - m2) * iv2 * g2v[7] + b2v[7];
    float* orow = out + (size_t)(m0 + row) * Cz;
    ((float4*)orow)[lane * 2] = oa;
    ((float4*)orow)[lane * 2 + 1] = ob;
  }
}

// ---------------------------------------------------------------------------
extern "C" void kernel_launch(void* const* d_in, const int* in_sizes, int n_in,
                              void* d_out, int out_size, void* d_ws,
                              size_t ws_size, hipStream_t stream) {
  const float* x = (const float*)d_in[0];
  const float* pw_w = (const float*)d_in[1];
  const float* pw_b = (const float*)d_in[2];
  const float* pw_bn_g = (const float*)d_in[3];
  const float* pw_bn_b = (const float*)d_in[4];
  const float* pw_bn_m = (const float*)d_in[5];
  const float* pw_bn_v = (const float*)d_in[6];
  const float* dw_w0 = (const float*)d_in[7];
  const float* dw_w1 = (const float*)d_in[8];
  const float* dw_w2 = (const float*)d_in[9];
  const float* dw_w3 = (const float*)d_in[10];
  const float* dw_b = (const float*)d_in[11];
  const float* dw_bn_g = (const float*)d_in[12];
  const float* dw_bn_b = (const float*)d_in[13];
  const float* dw_bn_m = (const float*)d_in[14];
  const float* dw_bn_v = (const float*)d_in[15];
  const float* se_w1 = (const float*)d_in[16];
  const float* se_b1 = (const float*)d_in[17];
  const float* se_w2 = (const float*)d_in[18];
  const float* se_b2 = (const float*)d_in[19];
  const float* se_ln_g = (const float*)d_in[20];
  const float* se_ln_b = (const float*)d_in[21];
  // d_in[22] = df_ln_g (unused: LN of channel-constant rows -> bias only)
  const float* df_ln_b = (const float*)d_in[23];
  const float* wq = (const float*)d_in[24];
  const float* bq = (const float*)d_in[25];
  const float* wv = (const float*)d_in[26];
  const float* bv = (const float*)d_in[27];
  const float* wg = (const float*)d_in[28];
  const float* bg = (const float*)d_in[29];
  const float* op_w = (const float*)d_in[30];
  const float* op_b = (const float*)d_in[31];
  const float* op_ln_g = (const float*)d_in[32];
  const float* op_ln_b = (const float*)d_in[33];
  const float* fn_g = (const float*)d_in[34];
  const float* fn_b = (const float*)d_in[35];
  float* out = (float*)d_out;

  const size_t NBL = (size_t)Bz * Cz * Lz;  // 8388608 elems
  char* p = (char*)d_ws;
  p += NBL * 2;                              // spare
  u16* xpw = (u16*)p; p += NBL * 2;          // 16MB
  u16* ybuf = (u16*)p; p += 4 * NBL * 2;     // 64MB
  u16* ebuf = (u16*)p; p += 4 * NBL * 2;     // 64MB
  u16* pwwbf = (u16*)p; p += (size_t)Cz * Cz * 2;    // 512KB
  u16* wvbf = (u16*)p; p += (size_t)DHz * Cz * 2;    // 256KB
  u16* opwbf = (u16*)p; p += (size_t)Cz * Cz * 2;    // 512KB
  float* fbuf = (float*)p;
  float* ysum = fbuf;                  // 16384
  float* scv = fbuf + 16384;           // 16384
  float* scores = fbuf + 32768;        // 65536
  float* pwA = fbuf + 98304;           // 512
  float* pwB = pwA + 512;              // 512
  float* dwA = pwB + 512;              // 2048
  float* dwB = dwA + 2048;             // 2048
  float* qc = dwB + 2048;              // 256

  prep_cvt_kernel<<<326, 256, 0, stream>>>(
      pw_w, wv, op_w, pwwbf, wvbf, opwbf, pw_b, pw_bn_g, pw_bn_b, pw_bn_m,
      pw_bn_v, dw_b, dw_bn_g, dw_bn_b, dw_bn_m, dw_bn_v, df_ln_b, wq, bq, pwA,
      pwB, dwA, dwB, qc);

  pw_mfma_kernel<<<Bz * (Lz / 32), 256, 0, stream>>>(pwwbf, x, pwA, pwB, xpw);

  dw_conv_kernel<<<Bz * Cz, 256, 0, stream>>>(xpw, dw_w0, dw_w1, dw_w2, dw_w3,
                                              dwA, dwB, ybuf, ysum);

  se_kernel<<<32, 128, 0, stream>>>(ysum, se_w1, se_b1, se_w2, se_b2, scv);

  ln_transpose_kernel<<<dim3(Lz / 32, 4 * Bz), 256, 0, stream>>>(
      ybuf, scv, se_ln_g, se_ln_b, ebuf);

  score_mfma_kernel<<<dim3(MT / 64, 4), 256, 0, stream>>>(
      ebuf, ebuf + NBL, ebuf + 2 * NBL, ebuf + 3 * NBL, wvbf, bv, qc, wg, bg,
      scores);

  op_mfma_kernel<<<MT / 32, 256, 0, stream>>>(
      ebuf, ebuf + NBL, ebuf + 2 * NBL, ebuf + 3 * NBL, scores, opwbf, op_b,
      op_ln_g, op_ln_b, x, fn_g, fn_b, out);
}